// Round 11
// baseline (855.707 us; speedup 1.0000x reference)
//
#include <hip/hip_runtime.h>
#include <hip/hip_fp16.h>
#include <cstdint>
#include <math.h>

typedef _Float16 h2 __attribute__((ext_vector_type(2)));
typedef float f32x2 __attribute__((ext_vector_type(2)));

__device__ __forceinline__ h2 f2h2(float a, float b) {
    h2 r; r.x = (_Float16)a; r.y = (_Float16)b; return r;
}
__device__ __forceinline__ float fdot2f(h2 a, h2 b, float c) {
    return __builtin_amdgcn_fdot2(a, b, c, false);
}
__device__ __forceinline__ f32x2 bc2(float x) { f32x2 r; r.x = x; r.y = x; return r; }
__device__ __forceinline__ f32x2 cvt2(h2 v) {
    f32x2 r; r.x = (float)v.x; r.y = (float)v.y; return r;
}
__device__ __forceinline__ f32x2 mk2(float a, float b) { f32x2 r; r.x = a; r.y = b; return r; }

// 16-byte-aligned fragment: 8 halfs, loadable as one float4.
union f4h {
    float4 f;
    h2 h[4];
    __half2 u[4];
};
// 8-byte pair of half2 for paired stores.
union h2x2 {
    float2 f;
    __half2 h[2];
};

// ---------------------------------------------------------------------------
// Threefry-2x32-20, exactly as JAX lowers it.
// ---------------------------------------------------------------------------
__device__ __forceinline__ uint32_t rotl32(uint32_t x, uint32_t n) {
    return (x << n) | (x >> (32u - n));
}

__device__ __forceinline__ void tf2x32(uint32_t k0, uint32_t k1,
                                       uint32_t x0, uint32_t x1,
                                       uint32_t& o0, uint32_t& o1) {
    uint32_t k2 = k0 ^ k1 ^ 0x1BD11BDAu;
    x0 += k0; x1 += k1;
    x0 += x1; x1 = rotl32(x1, 13); x1 ^= x0;
    x0 += x1; x1 = rotl32(x1, 15); x1 ^= x0;
    x0 += x1; x1 = rotl32(x1, 26); x1 ^= x0;
    x0 += x1; x1 = rotl32(x1, 6);  x1 ^= x0;
    x0 += k1; x1 += k2 + 1u;
    x0 += x1; x1 = rotl32(x1, 17); x1 ^= x0;
    x0 += x1; x1 = rotl32(x1, 29); x1 ^= x0;
    x0 += x1; x1 = rotl32(x1, 16); x1 ^= x0;
    x0 += x1; x1 = rotl32(x1, 24); x1 ^= x0;
    x0 += k2; x1 += k0 + 2u;
    x0 += x1; x1 = rotl32(x1, 13); x1 ^= x0;
    x0 += x1; x1 = rotl32(x1, 15); x1 ^= x0;
    x0 += x1; x1 = rotl32(x1, 26); x1 ^= x0;
    x0 += x1; x1 = rotl32(x1, 6);  x1 ^= x0;
    x0 += k0; x1 += k1 + 3u;
    x0 += x1; x1 = rotl32(x1, 17); x1 ^= x0;
    x0 += x1; x1 = rotl32(x1, 29); x1 ^= x0;
    x0 += x1; x1 = rotl32(x1, 16); x1 ^= x0;
    x0 += x1; x1 = rotl32(x1, 24); x1 ^= x0;
    x0 += k1; x1 += k2 + 4u;
    x0 += x1; x1 = rotl32(x1, 13); x1 ^= x0;
    x0 += x1; x1 = rotl32(x1, 15); x1 ^= x0;
    x0 += x1; x1 = rotl32(x1, 26); x1 ^= x0;
    x0 += x1; x1 = rotl32(x1, 6);  x1 ^= x0;
    x0 += k2; x1 += k0 + 5u;
    o0 = x0; o1 = x1;
}

__device__ float gumbel_at(int n, int which, int N) {
    uint32_t a0, a1, b0, b1;
    tf2x32(0u, 42u, 0u, 2u, a0, a1);   // constant-folded by compiler
    tf2x32(0u, 42u, 1u, 3u, b0, b1);
    uint32_t gk0 = which ? a1 : a0;
    uint32_t gk1 = which ? b1 : b0;
    int half = N >> 1;
    uint32_t o0, o1, bits;
    if (n < half) { tf2x32(gk0, gk1, (uint32_t)n, (uint32_t)(n + half), o0, o1); bits = o0; }
    else          { tf2x32(gk0, gk1, (uint32_t)(n - half), (uint32_t)n, o0, o1); bits = o1; }
    float f = __uint_as_float((bits >> 9) | 0x3F800000u) - 1.0f;
    float u = fmaxf(1.17549435e-38f, f);
    return -logf(-logf(u));
}

__device__ __forceinline__ uint32_t fmono(float f) {
    uint32_t b = __float_as_uint(f);
    return (b & 0x80000000u) ? ~b : (b | 0x80000000u);
}
__device__ __forceinline__ float funmono(uint32_t u) {
    uint32_t b = (u & 0x80000000u) ? (u & 0x7FFFFFFFu) : ~u;
    return __uint_as_float(b);
}

// online logsumexp merge: (m,s) <- merge((m,s),(m2,s2))
__device__ __forceinline__ void lse_merge(float& m, float& s, float m2, float s2) {
    float M = fmaxf(m, m2);
    float a = (m == -INFINITY) ? 0.f : expf(m - M) * s;
    float b = (m2 == -INFINITY) ? 0.f : expf(m2 - M) * s2;
    m = M; s = a + b;
}

#define NEGF (-1e9f)
#define ATTNGRID 2048  /* persistent attn blocks */

// ---------------------------------------------------------------------------
// CSR build
// ---------------------------------------------------------------------------
__global__ void k_hist(const int* __restrict__ dstp, int* __restrict__ deg, int E) {
    int e = blockIdx.x * 256 + threadIdx.x;
    if (e < E) atomicAdd(&deg[dstp[e]], 1);
}

__global__ void k_scan1(const int* __restrict__ deg, int* __restrict__ bsum, int N) {
    __shared__ int s[256];
    int i = blockIdx.x * 256 + threadIdx.x;
    s[threadIdx.x] = (i < N) ? deg[i] : 0;
    __syncthreads();
    for (int st = 128; st > 0; st >>= 1) {
        if (threadIdx.x < st) s[threadIdx.x] += s[threadIdx.x + st];
        __syncthreads();
    }
    if (threadIdx.x == 0) bsum[blockIdx.x] = s[0];
}

__global__ void k_scan2(int* __restrict__ bsum, int nb) {
    __shared__ int s[256];
    int i = threadIdx.x;
    int v = (i < nb) ? bsum[i] : 0;
    s[i] = v;
    __syncthreads();
    for (int st = 1; st < 256; st <<= 1) {
        int t = (i >= st) ? s[i - st] : 0;
        __syncthreads();
        s[i] += t;
        __syncthreads();
    }
    if (i < nb) bsum[i] = s[i] - v;  // exclusive
}

__global__ void k_scan3(const int* __restrict__ deg, const int* __restrict__ bsum,
                        int* __restrict__ rowptr, int* __restrict__ cursor, int N) {
    __shared__ int s[256];
    int i = blockIdx.x * 256 + threadIdx.x;
    int v = (i < N) ? deg[i] : 0;
    s[threadIdx.x] = v;
    __syncthreads();
    for (int st = 1; st < 256; st <<= 1) {
        int t = (threadIdx.x >= st) ? s[threadIdx.x - st] : 0;
        __syncthreads();
        s[threadIdx.x] += t;
        __syncthreads();
    }
    int excl = s[threadIdx.x] - v + bsum[blockIdx.x];
    if (i < N) { rowptr[i] = excl; cursor[i] = excl; }
}

__global__ void k_fill(const int* __restrict__ dstp, const int* __restrict__ srcp,
                       const float* __restrict__ lat, int* __restrict__ cursor,
                       int2* __restrict__ srclat, int E) {
    int e = blockIdx.x * 256 + threadIdx.x;
    if (e < E) {
        int pos = atomicAdd(&cursor[dstp[e]], 1);
        srclat[pos] = make_int2(srcp[e], __float_as_int(lat[e]));
    }
}

// ---------------------------------------------------------------------------
// k_qkvr: batched GEMV via fp16 dot2 (fp32 accum). Weights in LDS as half2
// d-pairs (~37 KB -> 4 blocks/CU). Grid 1024 GRID-STRIDE (weight staging is
// outside the tile loop; exact-tile grid paid 50% more staging - R10 lesson).
// BN fused into x-staging. Paired 8B fp16 stores.
// ---------------------------------------------------------------------------
__global__ __launch_bounds__(512, 4) void k_qkvr(
        const float* __restrict__ xin, const float* __restrict__ nt,
        const float* __restrict__ rq, int din, int N,
        const float* __restrict__ Wq, const float* __restrict__ bq,
        const float* __restrict__ Wk, const float* __restrict__ bk,
        const float* __restrict__ Wv, const float* __restrict__ bv,
        const float* __restrict__ Ws, const float* __restrict__ bs,
        const double* __restrict__ SUM, const double* __restrict__ SUMSQ,
        const float* __restrict__ bng, const float* __restrict__ bnb,
        int applyBN,
        __half* __restrict__ Q, __half* __restrict__ KV, __half* __restrict__ R) {
    __shared__ h2 w2[4][16 * 128];     // 32 KB max
    __shared__ float bias[4][128];
    __shared__ h2 xs2[32][17];
    __shared__ float sscale[32], sshift[32];
    int t = threadIdx.x;
    int dpCount = din >> 1;            // 16 or 1
    for (int i = t; i < dpCount * 128; i += 512) {
        int dp = i >> 7, j = i & 127;
        w2[0][i] = f2h2(Wq[(size_t)(2 * dp) * 128 + j], Wq[(size_t)(2 * dp + 1) * 128 + j]);
        w2[1][i] = f2h2(Wk[(size_t)(2 * dp) * 128 + j], Wk[(size_t)(2 * dp + 1) * 128 + j]);
        w2[2][i] = f2h2(Wv[(size_t)(2 * dp) * 128 + j], Wv[(size_t)(2 * dp + 1) * 128 + j]);
        w2[3][i] = f2h2(Ws[(size_t)(2 * dp) * 128 + j], Ws[(size_t)(2 * dp + 1) * 128 + j]);
    }
    if (t < 128) {
        bias[0][t] = bq[t]; bias[1][t] = bk[t]; bias[2][t] = bv[t]; bias[3][t] = bs[t];
    }
    if (t < 32) {
        if (applyBN) {
            double m = SUM[t] / N;
            double v = SUMSQ[t] / N - m * m;
            float inv = rsqrtf((float)v + 1e-5f);
            float sc = inv * bng[t];
            sscale[t] = sc;
            sshift[t] = bnb[t] - (float)m * sc;
        } else {
            sscale[t] = 1.f; sshift[t] = 0.f;
        }
    }
    int quad = t & 31;
    int sub = t >> 5;   // 0..15, two nodes each
    int dpsh = (din == 32) ? 4 : 0;
    int tiles = (N + 31) >> 5;
    for (int tile = blockIdx.x; tile < tiles; tile += gridDim.x) {
        int base = tile << 5;
        __syncthreads();
        for (int i = t; i < 32 * dpCount; i += 512) {
            int nl = i >> dpsh, dp = i & (dpCount - 1);
            int nn = base + nl;
            float x0 = 0.f, x1 = 0.f;
            if (nn < N) {
                if (din == 2) { x0 = nt[nn]; x1 = rq[nn]; }
                else {
                    x0 = xin[(size_t)nn * din + 2 * dp];
                    x1 = xin[(size_t)nn * din + 2 * dp + 1];
                }
            }
            x0 = x0 * sscale[2 * dp] + sshift[2 * dp];
            x1 = x1 * sscale[2 * dp + 1] + sshift[2 * dp + 1];
            xs2[nl][dp] = f2h2(x0, x1);
        }
        __syncthreads();
        float acc[4][2][4];  // [mat][node][comp]
#pragma unroll
        for (int m = 0; m < 4; ++m)
#pragma unroll
            for (int k = 0; k < 2; ++k)
#pragma unroll
                for (int c = 0; c < 4; ++c) acc[m][k][c] = bias[m][quad * 4 + c];
        for (int dp = 0; dp < dpCount; ++dp) {
            h2 xv0 = xs2[sub * 2 + 0][dp];
            h2 xv1 = xs2[sub * 2 + 1][dp];
#pragma unroll
            for (int m = 0; m < 4; ++m) {
                const h2* wp = &w2[m][dp * 128 + quad * 4];
                h2 wa = wp[0], wb = wp[1], wc = wp[2], wd = wp[3];
                acc[m][0][0] = fdot2f(xv0, wa, acc[m][0][0]);
                acc[m][0][1] = fdot2f(xv0, wb, acc[m][0][1]);
                acc[m][0][2] = fdot2f(xv0, wc, acc[m][0][2]);
                acc[m][0][3] = fdot2f(xv0, wd, acc[m][0][3]);
                acc[m][1][0] = fdot2f(xv1, wa, acc[m][1][0]);
                acc[m][1][1] = fdot2f(xv1, wb, acc[m][1][1]);
                acc[m][1][2] = fdot2f(xv1, wc, acc[m][1][2]);
                acc[m][1][3] = fdot2f(xv1, wd, acc[m][1][3]);
            }
        }
#pragma unroll
        for (int k = 0; k < 2; ++k) {
            int n = base + sub * 2 + k;
            if (n < N) {
                h2x2 v;
                v.h[0] = __floats2half2_rn(acc[0][k][0], acc[0][k][1]);
                v.h[1] = __floats2half2_rn(acc[0][k][2], acc[0][k][3]);
                *(float2*)&Q[(size_t)n * 128 + quad * 4] = v.f;
                v.h[0] = __floats2half2_rn(acc[1][k][0], acc[1][k][1]);
                v.h[1] = __floats2half2_rn(acc[1][k][2], acc[1][k][3]);
                *(float2*)&KV[(size_t)n * 256 + quad * 4] = v.f;
                v.h[0] = __floats2half2_rn(acc[2][k][0], acc[2][k][1]);
                v.h[1] = __floats2half2_rn(acc[2][k][2], acc[2][k][3]);
                *(float2*)&KV[(size_t)n * 256 + 128 + quad * 4] = v.f;
                v.h[0] = __floats2half2_rn(acc[3][k][0], acc[3][k][1]);
                v.h[1] = __floats2half2_rn(acc[3][k][2], acc[3][k][3]);
                *(float2*)&R[(size_t)n * 128 + quad * 4] = v.f;
            }
        }
    }
}

// ---------------------------------------------------------------------------
// k_attn: PURE attention. 2 nodes x 2 slots x 16 lanes per wave (R7 winner).
// ---------------------------------------------------------------------------
__global__ __launch_bounds__(256) void k_attn(
        const int2* __restrict__ srclat,
        const __half* __restrict__ Q, const __half* __restrict__ KV,
        const float* __restrict__ We,
        const __half* __restrict__ R, const float* __restrict__ Wb,
        const int* __restrict__ rowptr, const int* __restrict__ deg,
        __half* __restrict__ A, int N) {
    __shared__ float weL[128], wboL[128], wbrL[128];
    int t = threadIdx.x;
    if (t < 128) {
        float w0 = Wb[t], w1 = Wb[128 + t], w2v = Wb[256 + t];
        weL[t] = We[t];
        wboL[t] = w0 + w2v;
        wbrL[t] = w1 - w2v;
    }
    __syncthreads();

    int wvid = t >> 6;
    int l64 = t & 63;
    int slot = (l64 >> 4) & 1;  // 0..1: 2 edges per node per iteration
    int nsub = l64 >> 5;        // 0..1: which node this lane serves
    int lane = l64 & 15;        // 16 lanes x 8 halfs = 128 channels
    const f32x2* wep = (const f32x2*)&weL[lane * 8];
    const f32x2* bop = (const f32x2*)&wboL[lane * 8];
    const f32x2* brp = (const f32x2*)&wbrL[lane * 8];
    h2 weh0, weh1, weh2, weh3;
    {
        f32x2 wa = wep[0], wb = wep[1], wc = wep[2], wd = wep[3];
        weh0 = f2h2(wa.x, wa.y); weh1 = f2h2(wb.x, wb.y);
        weh2 = f2h2(wc.x, wc.y); weh3 = f2h2(wd.x, wd.y);
    }
    const float4 f4z = make_float4(0.f, 0.f, 0.f, 0.f);

    int T = gridDim.x * 4;      // waves
    int T2 = T * 2;             // nodes per sweep
    int base0 = (blockIdx.x * 4 + wvid) * 2;   // wave-uniform first node

    f4h qh, rh, k0, v0;
    int start = 0, d = 0; float l0 = 0.f;
    f4h pq, pr, pk, pv;
    float pl = 0.f;
    int s1 = 0, d1 = 0;
    int2 psl1 = make_int2(0, 0);
    int s2 = 0, d2 = 0;
    qh.f = f4z; rh.f = f4z; k0.f = f4z; v0.f = f4z;
    pq.f = f4z; pr.f = f4z; pk.f = f4z; pv.f = f4z;

    {
        int n0l = base0 + nsub;
        if (n0l < N) {
            start = rowptr[n0l]; d = deg[n0l];
            qh.f = *(const float4*)(Q + (size_t)n0l * 128 + lane * 8);
            rh.f = *(const float4*)(R + (size_t)n0l * 128 + lane * 8);
            if (slot < d) {
                int2 sl = srclat[start + slot];
                l0 = __int_as_float(sl.y);
                k0.f = *(const float4*)(KV + (size_t)sl.x * 256 + lane * 8);
                v0.f = *(const float4*)(KV + (size_t)sl.x * 256 + 128 + lane * 8);
            }
            int n1l = n0l + T2;
            if (n1l < N) {
                s1 = rowptr[n1l]; d1 = deg[n1l];
                if (slot < d1) psl1 = srclat[s1 + slot];
            }
            int n2l = n0l + 2 * T2;
            if (n2l < N) { s2 = rowptr[n2l]; d2 = deg[n2l]; }
        }
    }

    for (int nb = base0; nb < N; nb += T2) {
        int n = nb + nsub;
        int n1 = n + T2, n2 = n + 2 * T2, n3 = n + 3 * T2;
        int s3 = 0, d3 = 0;
        if (n3 < N) { s3 = rowptr[n3]; d3 = deg[n3]; }
        int2 psl2 = make_int2(0, 0);
        if (n2 < N && slot < d2) psl2 = srclat[s2 + slot];
        if (n1 < N) {
            pq.f = *(const float4*)(Q + (size_t)n1 * 128 + lane * 8);
            pr.f = *(const float4*)(R + (size_t)n1 * 128 + lane * 8);
            if (slot < d1) {
                pl = __int_as_float(psl1.y);
                pk.f = *(const float4*)(KV + (size_t)psl1.x * 256 + lane * 8);
                pv.f = *(const float4*)(KV + (size_t)psl1.x * 256 + 128 + lane * 8);
            }
        }

        float qwe = fdot2f(qh.h[0], weh0, fdot2f(qh.h[1], weh1,
                    fdot2f(qh.h[2], weh2, fdot2f(qh.h[3], weh3, 0.f))));
        qwe += __shfl_xor(qwe, 1); qwe += __shfl_xor(qwe, 2);

        float m = -INFINITY, den = 0.f, plsum = 0.f;
        f32x2 A0 = bc2(0.f), A1 = bc2(0.f), A2 = bc2(0.f), A3 = bc2(0.f);

        int idx = slot;
        bool have = idx < d;
        while (have) {
            int idx2 = idx + 2;
            bool have2 = idx2 < d;
            float l1 = 0.f;
            f4h k1, v1;
            if (have2) {
                int2 sl = srclat[start + idx2];
                l1 = __int_as_float(sl.y);
                k1.f = *(const float4*)(KV + (size_t)sl.x * 256 + lane * 8);
                v1.f = *(const float4*)(KV + (size_t)sl.x * 256 + 128 + lane * 8);
            }

            float t0 = fdot2f(qh.h[0], k0.h[0], fdot2f(qh.h[1], k0.h[1],
                       fdot2f(qh.h[2], k0.h[2], fdot2f(qh.h[3], k0.h[3], 0.f))));
            t0 += __shfl_xor(t0, 1); t0 += __shfl_xor(t0, 2);
            float alpha = fmaf(l0, qwe, t0) * 0.17677669529663687f;

            float mn = fmaxf(m, alpha);
            float sc = __expf(m - mn);
            float p = __expf(alpha - mn);
            f32x2 sc2 = bc2(sc), p2 = bc2(p);
            A0 = A0 * sc2 + p2 * cvt2(v0.h[0]);
            A1 = A1 * sc2 + p2 * cvt2(v0.h[1]);
            A2 = A2 * sc2 + p2 * cvt2(v0.h[2]);
            A3 = A3 * sc2 + p2 * cvt2(v0.h[3]);
            plsum = plsum * sc + p * l0;
            den = fmaf(den, sc, p);
            m = mn;

            idx = idx2; l0 = l1;
            k0.f = k1.f; v0.f = v1.f;
            have = have2;
        }

        // combine the 2 slots (xor 16 stays within this node's 32 lanes)
        {
            float mo = __shfl_xor(m, 16);
            float mn = fmaxf(m, mo);
            float sc = (m == -INFINITY) ? 0.f : __expf(m - mn);
            f32x2 sc2 = bc2(sc);
            A0 *= sc2; A1 *= sc2; A2 *= sc2; A3 *= sc2;
            den *= sc; plsum *= sc;
            A0 += mk2(__shfl_xor(A0.x, 16), __shfl_xor(A0.y, 16));
            A1 += mk2(__shfl_xor(A1.x, 16), __shfl_xor(A1.y, 16));
            A2 += mk2(__shfl_xor(A2.x, 16), __shfl_xor(A2.y, 16));
            A3 += mk2(__shfl_xor(A3.x, 16), __shfl_xor(A3.y, 16));
            den += __shfl_xor(den, 16); plsum += __shfl_xor(plsum, 16);
            m = mn;
        }

        float inv = 1.f / (den + 1e-16f);
        f32x2 inv2 = bc2(inv), pls2 = bc2(plsum);
        f32x2 O0 = (A0 + pls2 * wep[0]) * inv2;
        f32x2 O1 = (A1 + pls2 * wep[1]) * inv2;
        f32x2 O2 = (A2 + pls2 * wep[2]) * inv2;
        f32x2 O3 = (A3 + pls2 * wep[3]) * inv2;

        f32x2 R0 = cvt2(rh.h[0]), R1 = cvt2(rh.h[1]);
        f32x2 R2 = cvt2(rh.h[2]), R3 = cvt2(rh.h[3]);
        f32x2 G = O0 * bop[0];
        G += R0 * brp[0];
        G += O1 * bop[1]; G += R1 * brp[1];
        G += O2 * bop[2]; G += R2 * brp[2];
        G += O3 * bop[3]; G += R3 * brp[3];
        float g = G.x + G.y;
        g += __shfl_xor(g, 1); g += __shfl_xor(g, 2);
        g += __shfl_xor(g, 4); g += __shfl_xor(g, 8);
        float beta = 1.0f / (1.0f + __expf(-g));

        if ((l64 & 16) == 0 && n < N) {
            f32x2 bb = bc2(beta), ib = bc2(1.0f - beta);
            f32x2 W0 = bb * R0 + ib * O0;
            f32x2 W1 = bb * R1 + ib * O1;
            f32x2 W2 = bb * R2 + ib * O2;
            f32x2 W3 = bb * R3 + ib * O3;
            *(__half2*)&A[(size_t)n * 128 + lane * 8 + 0] = __floats2half2_rn(W0.x, W0.y);
            *(__half2*)&A[(size_t)n * 128 + lane * 8 + 2] = __floats2half2_rn(W1.x, W1.y);
            *(__half2*)&A[(size_t)n * 128 + lane * 8 + 4] = __floats2half2_rn(W2.x, W2.y);
            *(__half2*)&A[(size_t)n * 128 + lane * 8 + 6] = __floats2half2_rn(W3.x, W3.y);
        }

        qh.f = pq.f; rh.f = pr.f; k0.f = pk.f; v0.f = pv.f; l0 = pl;
        start = s1; d = d1;
        s1 = s2; d1 = d2; s2 = s3; d2 = d3;
        psl1 = psl2;
    }
}

// ---------------------------------------------------------------------------
// k_linstats: Y = relu(A(fp16) @ tW + tb) via fp16 dot2. Per-block stat
// partials with PLAIN stores (no fence/counter — device-scope fences cost
// ~100 µs/kernel on 8-XCD MI355X; dedicated k_statred is 40x cheaper).
// ---------------------------------------------------------------------------
__global__ __launch_bounds__(256) void k_linstats(
        const __half* __restrict__ A, const float* __restrict__ tW,
        const float* __restrict__ tb, float* __restrict__ H32,
        double* __restrict__ partials, int N) {
    __shared__ h2 w2l[64 * 32];       // 8 KB
    __shared__ float bias[32];
    __shared__ h2 xsT[64][66];        // ~16.9 KB, dp-major
    __shared__ double sp1[4][8][4], sp2[4][8][4];
    int t = threadIdx.x;
    for (int i = t; i < 64 * 32; i += 256) {
        int dp = i >> 5, j = i & 31;
        w2l[i] = f2h2(tW[(size_t)(2 * dp) * 32 + j], tW[(size_t)(2 * dp + 1) * 32 + j]);
    }
    if (t < 32) bias[t] = tb[t];
    int quad = t & 7;
    int sub = t >> 3;
    int base = blockIdx.x << 6;

    __syncthreads();
#pragma unroll
    for (int k = 0; k < 4; ++k) {
        int i = t + 256 * k;
        int nl = i >> 4, g8 = i & 15;
        int n = base + nl;
        h2 hv[4];
        if (n < N) {
            const h2* ap = (const h2*)(A + (size_t)n * 128 + g8 * 8);
            hv[0] = ap[0]; hv[1] = ap[1]; hv[2] = ap[2]; hv[3] = ap[3];
        } else {
            h2 z; z.x = (_Float16)0.f; z.y = (_Float16)0.f;
            hv[0] = z; hv[1] = z; hv[2] = z; hv[3] = z;
        }
        xsT[g8 * 4 + 0][nl] = hv[0];
        xsT[g8 * 4 + 1][nl] = hv[1];
        xsT[g8 * 4 + 2][nl] = hv[2];
        xsT[g8 * 4 + 3][nl] = hv[3];
    }
    __syncthreads();

    float acc[2][4];
#pragma unroll
    for (int k = 0; k < 2; ++k)
#pragma unroll
        for (int c = 0; c < 4; ++c) acc[k][c] = bias[quad * 4 + c];
    for (int dp = 0; dp < 64; ++dp) {
        h2 x0 = xsT[dp][sub * 2 + 0];
        h2 x1 = xsT[dp][sub * 2 + 1];
        const h2* wp = &w2l[dp * 32 + quad * 4];
        h2 wa = wp[0], wb = wp[1], wc = wp[2], wd = wp[3];
        acc[0][0] = fdot2f(x0, wa, acc[0][0]);
        acc[0][1] = fdot2f(x0, wb, acc[0][1]);
        acc[0][2] = fdot2f(x0, wc, acc[0][2]);
        acc[0][3] = fdot2f(x0, wd, acc[0][3]);
        acc[1][0] = fdot2f(x1, wa, acc[1][0]);
        acc[1][1] = fdot2f(x1, wb, acc[1][1]);
        acc[1][2] = fdot2f(x1, wc, acc[1][2]);
        acc[1][3] = fdot2f(x1, wd, acc[1][3]);
    }
    double s1[4] = {0, 0, 0, 0}, s2[4] = {0, 0, 0, 0};
#pragma unroll
    for (int k = 0; k < 2; ++k) {
        int n = base + sub * 2 + k;
        if (n < N) {
            float4 yv;
            yv.x = fmaxf(acc[k][0], 0.f); yv.y = fmaxf(acc[k][1], 0.f);
            yv.z = fmaxf(acc[k][2], 0.f); yv.w = fmaxf(acc[k][3], 0.f);
            *(float4*)&H32[(size_t)n * 32 + quad * 4] = yv;
            s1[0] += yv.x; s1[1] += yv.y; s1[2] += yv.z; s1[3] += yv.w;
            s2[0] += (double)yv.x * yv.x; s2[1] += (double)yv.y * yv.y;
            s2[2] += (double)yv.z * yv.z; s2[3] += (double)yv.w * yv.w;
        }
    }
#pragma unroll
    for (int c = 0; c < 4; ++c) {
        s1[c] += __shfl_xor(s1[c], 8);  s2[c] += __shfl_xor(s2[c], 8);
        s1[c] += __shfl_xor(s1[c], 16); s2[c] += __shfl_xor(s2[c], 16);
        s1[c] += __shfl_xor(s1[c], 32); s2[c] += __shfl_xor(s2[c], 32);
    }
    __syncthreads();
    int wave = t >> 6;
    if ((t & 63) < 8) {
#pragma unroll
        for (int c = 0; c < 4; ++c) { sp1[wave][quad][c] = s1[c]; sp2[wave][quad][c] = s2[c]; }
    }
    __syncthreads();
    if (t < 32) {
        int q = t >> 2, c = t & 3;
        double a1 = 0, a2 = 0;
#pragma unroll
        for (int wv = 0; wv < 4; ++wv) { a1 += sp1[wv][q][c]; a2 += sp2[wv][q][c]; }
        partials[(size_t)blockIdx.x * 64 + t] = a1;
        partials[(size_t)blockIdx.x * 64 + 32 + t] = a2;
    }
}

// ---------------------------------------------------------------------------
// Single-kernel stat reduction: block = one output column (64 blocks).
// ---------------------------------------------------------------------------
__global__ void k_statred(const double* __restrict__ partials,
                          double* __restrict__ SUM, double* __restrict__ SUMSQ,
                          int nblocks) {
    __shared__ double s[256];
    int col = blockIdx.x;   // 0..63
    double a = 0;
    for (int b = threadIdx.x; b < nblocks; b += 256)
        a += partials[(size_t)b * 64 + col];
    s[threadIdx.x] = a;
    __syncthreads();
    for (int st = 128; st > 0; st >>= 1) {
        if (threadIdx.x < st) s[threadIdx.x] += s[threadIdx.x + st];
        __syncthreads();
    }
    if (threadIdx.x == 0) {
        if (col < 32) SUM[col] = s[0];
        else SUMSQ[col - 32] = s[0];
    }
}

// ---------------------------------------------------------------------------
// k_mlp12: FUSED BN affine + 32->128 relu + 128->64 relu. Y1 lives in LDS
// (16-node tiles). ~59.5 KB LDS -> 2 blocks/CU. Block 0 zero-inits head
// scratch (slot1/slot2/a1buf).
// ---------------------------------------------------------------------------
__global__ __launch_bounds__(256) void k_mlp12(
        const float* __restrict__ H32,
        const double* __restrict__ SUM, const double* __restrict__ SUMSQ,
        const float* __restrict__ bng, const float* __restrict__ bnb,
        const float* __restrict__ W1, const float* __restrict__ b1,
        const float* __restrict__ W2, const float* __restrict__ b2,
        float* __restrict__ Y2, unsigned int* __restrict__ smallbuf, int N) {
    __shared__ float w1[32 * 128];     // 16 KB
    __shared__ float sb1[128];
    __shared__ float sscale[32], sshift[32];
    __shared__ float w2f[128 * 64];    // 32 KB
    __shared__ float sb2[64];
    __shared__ float xs[16][36];       // 2.25 KB
    __shared__ float y1[16][132];      // 8.25 KB
    int t = threadIdx.x;
    if (blockIdx.x == 0 && t < 16) smallbuf[t] = 0u;  // zero 64 B head scratch
    for (int i = t; i < 32 * 128; i += 256) w1[i] = W1[i];
    for (int i = t; i < 128 * 64; i += 256) w2f[i] = W2[i];
    if (t < 128) sb1[t] = b1[t];
    if (t < 64) sb2[t] = b2[t];
    if (t < 32) {
        double m = SUM[t] / N;
        double v = SUMSQ[t] / N - m * m;
        float inv = rsqrtf((float)v + 1e-5f);
        float sc = inv * bng[t];
        sscale[t] = sc;
        sshift[t] = bnb[t] - (float)m * sc;
    }
    int q1 = t & 31, s1_ = t >> 5;     // phase1: 32 quads x 4 cols, 8 subs x 2 nodes
    int q2 = t & 15, s2_ = t >> 4;     // phase2: 16 quads x 4 cols, 16 nodes
    int tiles = (N + 15) >> 4;
    for (int tile = blockIdx.x; tile < tiles; tile += gridDim.x) {
        int base = tile << 4;
        __syncthreads();
        if (t < 128) {
            int nl = t >> 3, q = t & 7;
            int n = base + nl;
            float4 xv = make_float4(0.f, 0.f, 0.f, 0.f);
            if (n < N) xv = *(const float4*)&H32[(size_t)n * 32 + q * 4];
            xs[nl][q * 4 + 0] = xv.x * sscale[q * 4 + 0] + sshift[q * 4 + 0];
            xs[nl][q * 4 + 1] = xv.y * sscale[q * 4 + 1] + sshift[q * 4 + 1];
            xs[nl][q * 4 + 2] = xv.z * sscale[q * 4 + 2] + sshift[q * 4 + 2];
            xs[nl][q * 4 + 3] = xv.w * sscale[q * 4 + 3] + sshift[q * 4 + 3];
        }
        __syncthreads();
        // phase1: 32 -> 128, relu into y1 LDS
        float a[2][4];
#pragma unroll
        for (int k = 0; k < 2; ++k)
#pragma unroll
            for (int c = 0; c < 4; ++c) a[k][c] = sb1[q1 * 4 + c];
        for (int d = 0; d < 32; ++d) {
            float4 w4 = *(const float4*)&w1[d * 128 + q1 * 4];
#pragma unroll
            for (int k = 0; k < 2; ++k) {
                float x = xs[s1_ * 2 + k][d];
                a[k][0] = fmaf(x, w4.x, a[k][0]);
                a[k][1] = fmaf(x, w4.y, a[k][1]);
                a[k][2] = fmaf(x, w4.z, a[k][2]);
                a[k][3] = fmaf(x, w4.w, a[k][3]);
            }
        }
#pragma unroll
        for (int k = 0; k < 2; ++k) {
            float4 yv;
            yv.x = fmaxf(a[k][0], 0.f); yv.y = fmaxf(a[k][1], 0.f);
            yv.z = fmaxf(a[k][2], 0.f); yv.w = fmaxf(a[k][3], 0.f);
            *(float4*)&y1[s1_ * 2 + k][q1 * 4] = yv;
        }
        __syncthreads();
        // phase2: 128 -> 64, relu to global
        float b[4];
#pragma unroll
        for (int c = 0; c < 4; ++c) b[c] = sb2[q2 * 4 + c];
        for (int d = 0; d < 128; ++d) {
            float4 w4 = *(const float4*)&w2f[d * 64 + q2 * 4];
            float x = y1[s2_][d];
            b[0] = fmaf(x, w4.x, b[0]);
            b[1] = fmaf(x, w4.y, b[1]);
            b[2] = fmaf(x, w4.z, b[2]);
            b[3] = fmaf(x, w4.w, b[3]);
        }
        int n = base + s2_;
        if (n < N) {
            float4 yv;
            yv.x = fmaxf(b[0], 0.f); yv.y = fmaxf(b[1], 0.f);
            yv.z = fmaxf(b[2], 0.f); yv.w = fmaxf(b[3], 0.f);
            *(float4*)&Y2[(size_t)n * 64 + q2 * 4] = yv;
        }
    }
}

// ---------------------------------------------------------------------------
// k_mlp3h: 64->64 GEMV (X3) FUSED with head1 (logits1 + lse partials +
// per-block gumbel-argmax). __launch_bounds__(256,4) caps VGPR at 128
// (was 184 -> 2 blocks/CU, 6.5% occupancy, latency-starved at 50 µs).
// Grid 1024 grid-stride fills the 4 blocks/CU residency.
// ---------------------------------------------------------------------------
__global__ __launch_bounds__(256, 4) void k_mlp3h(
        const float* __restrict__ Y2, const float* __restrict__ W3,
        const float* __restrict__ b3,
        const float* __restrict__ remW, const float* __restrict__ remB,
        const int* __restrict__ active,
        float* __restrict__ X3, float* __restrict__ l1out,
        unsigned long long* __restrict__ slot1, float2* __restrict__ part1,
        int N) {
    __shared__ float w3[64 * 64];
    __shared__ float sb3[64];
    __shared__ float xs[32][68];
    __shared__ float srw[64];
    __shared__ float redm[256], reds[256];
    __shared__ unsigned long long redb[256];
    int t = threadIdx.x;
    for (int i = t; i < 64 * 64; i += 256) w3[i] = W3[i];
    if (t < 64) { sb3[t] = b3[t]; srw[t] = remW[t]; }
    float rB = remB[0];
    int quad = t & 15, sub = t >> 4;
    float lm = -INFINITY, ls = 0.f;
    unsigned long long best = 0ull;
    int tiles = (N + 31) >> 5;
    for (int tile = blockIdx.x; tile < tiles; tile += gridDim.x) {
        int base = tile << 5;
        __syncthreads();
#pragma unroll
        for (int k = 0; k < 2; ++k) {
            int i = t + 256 * k;
            int nl = i >> 4, q = i & 15;
            int n = base + nl;
            float4 xv = make_float4(0.f, 0.f, 0.f, 0.f);
            if (n < N) xv = *(const float4*)&Y2[(size_t)n * 64 + q * 4];
            *(float4*)&xs[nl][q * 4] = xv;
        }
        __syncthreads();
        float a[2][4];
#pragma unroll
        for (int k = 0; k < 2; ++k)
#pragma unroll
            for (int c = 0; c < 4; ++c) a[k][c] = sb3[quad * 4 + c];
        for (int d = 0; d < 64; ++d) {
            float4 w4 = *(const float4*)&w3[d * 64 + quad * 4];
#pragma unroll
            for (int k = 0; k < 2; ++k) {
                float x = xs[sub * 2 + k][d];
                a[k][0] = fmaf(x, w4.x, a[k][0]);
                a[k][1] = fmaf(x, w4.y, a[k][1]);
                a[k][2] = fmaf(x, w4.z, a[k][2]);
                a[k][3] = fmaf(x, w4.w, a[k][3]);
            }
        }
#pragma unroll
        for (int k = 0; k < 2; ++k) {
            int n = base + sub * 2 + k;
            if (n < N)
                *(float4*)&X3[(size_t)n * 64 + quad * 4] = *(float4*)a[k];
        }
        // fused head1: per-node dot with remW via 16-lane butterfly
#pragma unroll
        for (int k = 0; k < 2; ++k) {
            int n = base + sub * 2 + k;
            float h = a[k][0] * srw[quad * 4 + 0] + a[k][1] * srw[quad * 4 + 1]
                    + a[k][2] * srw[quad * 4 + 2] + a[k][3] * srw[quad * 4 + 3];
            h += __shfl_xor(h, 1); h += __shfl_xor(h, 2);
            h += __shfl_xor(h, 4); h += __shfl_xor(h, 8);
            if (quad == 0 && n < N) {
                float maskf = (active[n] == 1) ? 0.f : NEGF;
                float rm_ = (n < 15) ? ((maskf == 0.f) ? NEGF : 0.f) : maskf;
                float l1 = h + rB + rm_;
                l1out[n] = l1;
                lse_merge(lm, ls, l1, 1.0f);
                float z = l1 + gumbel_at(n, 0, N);
                unsigned long long p = ((unsigned long long)fmono(z) << 32) |
                                       (unsigned long long)(0xFFFFFFFFu - (unsigned)n);
                if (p > best) best = p;
            }
        }
    }
    // block reduce (m,s) + best
    redm[t] = lm; reds[t] = ls; redb[t] = best;
    __syncthreads();
    for (int st = 128; st > 0; st >>= 1) {
        if (t < st) {
            float m2 = redm[t + st], s2 = reds[t + st];
            float mm = redm[t], ss = reds[t];
            lse_merge(mm, ss, m2, s2);
            redm[t] = mm; reds[t] = ss;
            if (redb[t + st] > redb[t]) redb[t] = redb[t + st];
        }
        __syncthreads();
    }
    if (t == 0) {
        part1[blockIdx.x] = make_float2(redm[0], reds[0]);
        if (redb[0]) atomicMax(slot1, redb[0]);
    }
}

// ---------------------------------------------------------------------------
// Head kernels
// ---------------------------------------------------------------------------
__global__ void k_head2(const float* __restrict__ X3, const float* __restrict__ addW,
                        const float* __restrict__ addB,
                        const unsigned long long* __restrict__ slot1,
                        float* __restrict__ tvec, int* __restrict__ a1buf) {
    int j = threadIdx.x;  // 64
    unsigned long long p = *slot1;
    int a1 = (int)(0xFFFFFFFFu - (unsigned)(p & 0xFFFFFFFFull));
    const float* xr = X3 + (size_t)a1 * 64;
    float acc = addB[j];
    for (int d = 0; d < 64; d++) acc = fmaf(xr[d], addW[d * 64 + j], acc);
    tvec[j] = tanhf(acc);
    if (j == 0) *a1buf = a1;
}

// head3 with per-block logsumexp partials + per-block argmax atomic.
__global__ void k_head3p(const float* __restrict__ X3, const float* __restrict__ tvec,
                         const int* __restrict__ active, const int* __restrict__ a1buf,
                         float* __restrict__ l2out, unsigned long long* __restrict__ slot2,
                         float2* __restrict__ part2, int N) {
    __shared__ float redm[256], reds[256];
    __shared__ unsigned long long redb[256];
    int t = threadIdx.x;
    int n = blockIdx.x * 256 + t;
    float lm = -INFINITY, ls = 0.f;
    unsigned long long best = 0ull;
    if (n < N) {
        const float* xr = X3 + (size_t)n * 64;
        float acc = 0.f;
        for (int d = 0; d < 64; d++) acc = fmaf(xr[d], tvec[d], acc);
        float maskf = (active[n] == 1) ? 0.f : NEGF;
        if (n == *a1buf) maskf = 0.f;
        float l2 = acc + maskf;
        l2out[n] = l2;
        lm = l2; ls = 1.f;
        float z = l2 + gumbel_at(n, 1, N);
        best = ((unsigned long long)fmono(z) << 32) |
               (unsigned long long)(0xFFFFFFFFu - (unsigned)n);
    }
    redm[t] = lm; reds[t] = ls; redb[t] = best;
    __syncthreads();
    for (int st = 128; st > 0; st >>= 1) {
        if (t < st) {
            float mm = redm[t], ss = reds[t];
            lse_merge(mm, ss, redm[t + st], reds[t + st]);
            redm[t] = mm; reds[t] = ss;
            if (redb[t + st] > redb[t]) redb[t] = redb[t + st];
        }
        __syncthreads();
    }
    if (t == 0) {
        part2[blockIdx.x] = make_float2(redm[0], reds[0]);
        if (redb[0]) atomicMax(slot2, redb[0]);
    }
}

__global__ void k_final2(const float* __restrict__ l1, const float* __restrict__ l2,
                         const unsigned long long* __restrict__ slot2,
                         const int* __restrict__ a1buf,
                         const float2* __restrict__ part1, int np1,
                         const float2* __restrict__ part2, int np2,
                         float* __restrict__ outTail) {
    __shared__ float rm[256], rs[256];
    int t = threadIdx.x;
    // reduce part1
    float m = -INFINITY, s = 0.f;
    for (int i = t; i < np1; i += 256) { float2 p = part1[i]; lse_merge(m, s, p.x, p.y); }
    rm[t] = m; rs[t] = s;
    __syncthreads();
    for (int st = 128; st > 0; st >>= 1) {
        if (t < st) { float mm = rm[t], ss = rs[t]; lse_merge(mm, ss, rm[t + st], rs[t + st]); rm[t] = mm; rs[t] = ss; }
        __syncthreads();
    }
    float M1 = rm[0], S1 = rs[0];
    __syncthreads();
    // reduce part2
    m = -INFINITY; s = 0.f;
    for (int i = t; i < np2; i += 256) { float2 p = part2[i]; lse_merge(m, s, p.x, p.y); }
    rm[t] = m; rs[t] = s;
    __syncthreads();
    for (int st = 128; st > 0; st >>= 1) {
        if (t < st) { float mm = rm[t], ss = rs[t]; lse_merge(mm, ss, rm[t + st], rs[t + st]); rm[t] = mm; rs[t] = ss; }
        __syncthreads();
    }
    float M2 = rm[0], S2 = rs[0];
    if (t == 0) {
        int a1 = *a1buf;
        int a2 = (int)(0xFFFFFFFFu - (unsigned)((*slot2) & 0xFFFFFFFFull));
        outTail[0] = (float)a1;
        outTail[1] = (float)a2;
        outTail[2] = l1[a1] - (M1 + logf(S1));
        outTail[3] = l2[a2] - (M2 + logf(S2));
    }
}

// ---------------------------------------------------------------------------
// Host launcher
// ---------------------------------------------------------------------------
extern "C" void kernel_launch(void* const* d_in, const int* in_sizes, int n_in,
                              void* d_out, int out_size, void* d_ws, size_t ws_size,
                              hipStream_t stream) {
    const float* node_type = (const float*)d_in[0];
    const float* requests  = (const float*)d_in[1];
    const float* latency   = (const float*)d_in[2];
    const int* edge_index  = (const int*)d_in[3];
    const int* active      = (const int*)d_in[4];
    int N = in_sizes[0];
    int E = in_sizes[2];
    const int* src = edge_index;
    const int* dst = edge_index + E;
    float* out = (float*)d_out;

    char* base = (char*)d_ws;
    size_t off = 0;
    auto alloc = [&](size_t bytes) -> char* {
        char* p = base + off;
        off += (bytes + 255) & ~(size_t)255;
        return p;
    };
    char* Abuf   = alloc((size_t)N * 128 * 4);  // fp16 A; later fp32 Y2
    char* Qbuf   = alloc((size_t)N * 128 * 4);  // fp16 Q
    __half* KV   = (__half*)alloc((size_t)N * 256 * 2); // interleaved K,V fp16
    char* Rbuf   = alloc((size_t)N * 128 * 4);  // fp16 R; later fp32 X3
    float* H32   = (float*)alloc((size_t)N * 32 * 4);
    int* deg     = (int*)alloc((size_t)N * 4);
    int* rowptr  = (int*)alloc((size_t)N * 4);
    int* cursor  = (int*)alloc((size_t)N * 4);
    int2* srclat = (int2*)alloc((size_t)E * 8);
    int* bsum    = (int*)alloc(1024 * 4);
    int lsTiles = (N + 63) / 64;
    double* partials = (double*)alloc((size_t)lsTiles * 64 * 8);
    double* SUM  = (double*)alloc(512);
    double* SUMSQ = SUM + 32;
    float2* part1 = (float2*)alloc(1024 * 8);
    int ng = (N + 255) / 256;
    float2* part2 = (float2*)alloc((size_t)ng * 8);
    char* small  = alloc(1024);
    unsigned long long* slot1 = (unsigned long long*)small;
    unsigned long long* slot2 = slot1 + 1;
    int* a1buf = (int*)(small + 32);
    float* tvec = (float*)(small + 64);

    __half* Ah = (__half*)Abuf;   float* Y2f = (float*)Abuf;
    __half* Qh = (__half*)Qbuf;
    __half* Rh = (__half*)Rbuf;   float* X3f = (float*)Rbuf;

    int egE = (E + 255) / 256;
    int nb = ng;

    // ---- CSR build ----
    (void)hipMemsetAsync(deg, 0, (size_t)N * 4, stream);
    k_hist<<<egE, 256, 0, stream>>>(dst, deg, E);
    k_scan1<<<nb, 256, 0, stream>>>(deg, bsum, N);
    k_scan2<<<1, 256, 0, stream>>>(bsum, nb);
    k_scan3<<<nb, 256, 0, stream>>>(deg, bsum, rowptr, cursor, N);
    k_fill<<<egE, 256, 0, stream>>>(dst, src, latency, cursor, srclat, E);

    for (int L = 0; L < 5; ++L) {
        int din = L ? 32 : 2;
        const float* xin = L ? H32 : nullptr;
        const float* Wq = L ? (const float*)d_in[19] + (size_t)(L - 1) * 4096 : (const float*)d_in[5];
        const float* bq = L ? (const float*)d_in[20] + (size_t)(L - 1) * 128  : (const float*)d_in[6];
        const float* Wk = L ? (const float*)d_in[21] + (size_t)(L - 1) * 4096 : (const float*)d_in[7];
        const float* bk = L ? (const float*)d_in[22] + (size_t)(L - 1) * 128  : (const float*)d_in[8];
        const float* Wv = L ? (const float*)d_in[23] + (size_t)(L - 1) * 4096 : (const float*)d_in[9];
        const float* bv = L ? (const float*)d_in[24] + (size_t)(L - 1) * 128  : (const float*)d_in[10];
        const float* We = L ? (const float*)d_in[25] + (size_t)(L - 1) * 128  : (const float*)d_in[11];
        const float* Ws = L ? (const float*)d_in[26] + (size_t)(L - 1) * 4096 : (const float*)d_in[12];
        const float* bs = L ? (const float*)d_in[27] + (size_t)(L - 1) * 128  : (const float*)d_in[13];
        const float* Wb = L ? (const float*)d_in[28] + (size_t)(L - 1) * 384  : (const float*)d_in[14];
        const float* tW = L ? (const float*)d_in[29] + (size_t)(L - 1) * 4096 : (const float*)d_in[15];
        const float* tb = L ? (const float*)d_in[30] + (size_t)(L - 1) * 32   : (const float*)d_in[16];
        const float* bngP = (L == 1) ? (const float*)d_in[17]
                          : (L >= 2) ? (const float*)d_in[31] + (size_t)(L - 2) * 32 : nullptr;
        const float* bnbP = (L == 1) ? (const float*)d_in[18]
                          : (L >= 2) ? (const float*)d_in[32] + (size_t)(L - 2) * 32 : nullptr;

        k_qkvr<<<1024, 512, 0, stream>>>(xin, node_type, requests, din, N,
                                         Wq, bq, Wk, bk, Wv, bv, Ws, bs,
                                         SUM, SUMSQ, bngP, bnbP, (L > 0) ? 1 : 0,
                                         Qh, KV, Rh);
        k_attn<<<ATTNGRID, 256, 0, stream>>>(srclat, Qh, KV, We, Rh, Wb,
                                             rowptr, deg, Ah, N);
        k_linstats<<<lsTiles, 256, 0, stream>>>(Ah, tW, tb, H32, partials, N);
        k_statred<<<64, 256, 0, stream>>>(partials, SUM, SUMSQ, lsTiles);
    }

    // embedding MLP: H32 -> (Y1 in LDS) -> Y2(Abuf) -> X3(Rbuf) + fused head1
    k_mlp12<<<512, 256, 0, stream>>>(H32, SUM, SUMSQ,
                                     (const float*)d_in[31] + 3 * 32,
                                     (const float*)d_in[32] + 3 * 32,
                                     (const float*)d_in[33], (const float*)d_in[34],
                                     (const float*)d_in[35], (const float*)d_in[36],
                                     Y2f, (unsigned int*)small, N);
    k_mlp3h<<<1024, 256, 0, stream>>>(Y2f, (const float*)d_in[37], (const float*)d_in[38],
                                      (const float*)d_in[39], (const float*)d_in[40],
                                      active, X3f, out, slot1, part1, N);
    k_head2<<<1, 64, 0, stream>>>(X3f, (const float*)d_in[41], (const float*)d_in[42],
                                  slot1, tvec, a1buf);
    k_head3p<<<ng, 256, 0, stream>>>(X3f, tvec, active, a1buf, out + N, slot2,
                                     part2, N);
    k_final2<<<1, 256, 0, stream>>>(out, out + N, slot2, a1buf,
                                    part1, 1024, part2, ng, out + 2 * N);
}

// Round 12
// 684.272 us; speedup vs baseline: 1.2505x; 1.2505x over previous
//
#include <hip/hip_runtime.h>
#include <hip/hip_fp16.h>
#include <cstdint>
#include <math.h>

typedef _Float16 h2 __attribute__((ext_vector_type(2)));
typedef float f32x2 __attribute__((ext_vector_type(2)));

__device__ __forceinline__ h2 f2h2(float a, float b) {
    h2 r; r.x = (_Float16)a; r.y = (_Float16)b; return r;
}
__device__ __forceinline__ float fdot2f(h2 a, h2 b, float c) {
    return __builtin_amdgcn_fdot2(a, b, c, false);
}
__device__ __forceinline__ f32x2 bc2(float x) { f32x2 r; r.x = x; r.y = x; return r; }
__device__ __forceinline__ f32x2 cvt2(h2 v) {
    f32x2 r; r.x = (float)v.x; r.y = (float)v.y; return r;
}
__device__ __forceinline__ f32x2 mk2(float a, float b) { f32x2 r; r.x = a; r.y = b; return r; }

// 16-byte-aligned fragment: 8 halfs, loadable as one float4.
union f4h {
    float4 f;
    h2 h[4];
    __half2 u[4];
};

// ---------------------------------------------------------------------------
// Threefry-2x32-20, exactly as JAX lowers it.
// ---------------------------------------------------------------------------
__device__ __forceinline__ uint32_t rotl32(uint32_t x, uint32_t n) {
    return (x << n) | (x >> (32u - n));
}

__device__ __forceinline__ void tf2x32(uint32_t k0, uint32_t k1,
                                       uint32_t x0, uint32_t x1,
                                       uint32_t& o0, uint32_t& o1) {
    uint32_t k2 = k0 ^ k1 ^ 0x1BD11BDAu;
    x0 += k0; x1 += k1;
    x0 += x1; x1 = rotl32(x1, 13); x1 ^= x0;
    x0 += x1; x1 = rotl32(x1, 15); x1 ^= x0;
    x0 += x1; x1 = rotl32(x1, 26); x1 ^= x0;
    x0 += x1; x1 = rotl32(x1, 6);  x1 ^= x0;
    x0 += k1; x1 += k2 + 1u;
    x0 += x1; x1 = rotl32(x1, 17); x1 ^= x0;
    x0 += x1; x1 = rotl32(x1, 29); x1 ^= x0;
    x0 += x1; x1 = rotl32(x1, 16); x1 ^= x0;
    x0 += x1; x1 = rotl32(x1, 24); x1 ^= x0;
    x0 += k2; x1 += k0 + 2u;
    x0 += x1; x1 = rotl32(x1, 13); x1 ^= x0;
    x0 += x1; x1 = rotl32(x1, 15); x1 ^= x0;
    x0 += x1; x1 = rotl32(x1, 26); x1 ^= x0;
    x0 += x1; x1 = rotl32(x1, 6);  x1 ^= x0;
    x0 += k0; x1 += k1 + 3u;
    x0 += x1; x1 = rotl32(x1, 17); x1 ^= x0;
    x0 += x1; x1 = rotl32(x1, 29); x1 ^= x0;
    x0 += x1; x1 = rotl32(x1, 16); x1 ^= x0;
    x0 += x1; x1 = rotl32(x1, 24); x1 ^= x0;
    x0 += k1; x1 += k2 + 4u;
    x0 += x1; x1 = rotl32(x1, 13); x1 ^= x0;
    x0 += x1; x1 = rotl32(x1, 15); x1 ^= x0;
    x0 += x1; x1 = rotl32(x1, 26); x1 ^= x0;
    x0 += x1; x1 = rotl32(x1, 6);  x1 ^= x0;
    x0 += k2; x1 += k0 + 5u;
    o0 = x0; o1 = x1;
}

__device__ float gumbel_at(int n, int which, int N) {
    uint32_t a0, a1, b0, b1;
    tf2x32(0u, 42u, 0u, 2u, a0, a1);   // constant-folded by compiler
    tf2x32(0u, 42u, 1u, 3u, b0, b1);
    uint32_t gk0 = which ? a1 : a0;
    uint32_t gk1 = which ? b1 : b0;
    int half = N >> 1;
    uint32_t o0, o1, bits;
    if (n < half) { tf2x32(gk0, gk1, (uint32_t)n, (uint32_t)(n + half), o0, o1); bits = o0; }
    else          { tf2x32(gk0, gk1, (uint32_t)(n - half), (uint32_t)n, o0, o1); bits = o1; }
    float f = __uint_as_float((bits >> 9) | 0x3F800000u) - 1.0f;
    float u = fmaxf(1.17549435e-38f, f);
    return -logf(-logf(u));
}

__device__ __forceinline__ uint32_t fmono(float f) {
    uint32_t b = __float_as_uint(f);
    return (b & 0x80000000u) ? ~b : (b | 0x80000000u);
}
__device__ __forceinline__ float funmono(uint32_t u) {
    uint32_t b = (u & 0x80000000u) ? (u & 0x7FFFFFFFu) : ~u;
    return __uint_as_float(b);
}

// online logsumexp merge: (m,s) <- merge((m,s),(m2,s2))
__device__ __forceinline__ void lse_merge(float& m, float& s, float m2, float s2) {
    float M = fmaxf(m, m2);
    float a = (m == -INFINITY) ? 0.f : expf(m - M) * s;
    float b = (m2 == -INFINITY) ? 0.f : expf(m2 - M) * s2;
    m = M; s = a + b;
}

#define NEGF (-1e9f)
#define ATTNGRID 2048  /* persistent attn blocks */

// ---------------------------------------------------------------------------
// CSR build
// ---------------------------------------------------------------------------
__global__ void k_hist(const int* __restrict__ dstp, int* __restrict__ deg, int E) {
    int e = blockIdx.x * 256 + threadIdx.x;
    if (e < E) atomicAdd(&deg[dstp[e]], 1);
}

__global__ void k_scan1(const int* __restrict__ deg, int* __restrict__ bsum, int N) {
    __shared__ int s[256];
    int i = blockIdx.x * 256 + threadIdx.x;
    s[threadIdx.x] = (i < N) ? deg[i] : 0;
    __syncthreads();
    for (int st = 128; st > 0; st >>= 1) {
        if (threadIdx.x < st) s[threadIdx.x] += s[threadIdx.x + st];
        __syncthreads();
    }
    if (threadIdx.x == 0) bsum[blockIdx.x] = s[0];
}

__global__ void k_scan2(int* __restrict__ bsum, int nb) {
    __shared__ int s[256];
    int i = threadIdx.x;
    int v = (i < nb) ? bsum[i] : 0;
    s[i] = v;
    __syncthreads();
    for (int st = 1; st < 256; st <<= 1) {
        int t = (i >= st) ? s[i - st] : 0;
        __syncthreads();
        s[i] += t;
        __syncthreads();
    }
    if (i < nb) bsum[i] = s[i] - v;  // exclusive
}

__global__ void k_scan3(const int* __restrict__ deg, const int* __restrict__ bsum,
                        int* __restrict__ rowptr, int* __restrict__ cursor, int N) {
    __shared__ int s[256];
    int i = blockIdx.x * 256 + threadIdx.x;
    int v = (i < N) ? deg[i] : 0;
    s[threadIdx.x] = v;
    __syncthreads();
    for (int st = 1; st < 256; st <<= 1) {
        int t = (threadIdx.x >= st) ? s[threadIdx.x - st] : 0;
        __syncthreads();
        s[threadIdx.x] += t;
        __syncthreads();
    }
    int excl = s[threadIdx.x] - v + bsum[blockIdx.x];
    if (i < N) { rowptr[i] = excl; cursor[i] = excl; }
}

__global__ void k_fill(const int* __restrict__ dstp, const int* __restrict__ srcp,
                       const float* __restrict__ lat, int* __restrict__ cursor,
                       int2* __restrict__ srclat, int E) {
    int e = blockIdx.x * 256 + threadIdx.x;
    if (e < E) {
        int pos = atomicAdd(&cursor[dstp[e]], 1);
        srclat[pos] = make_int2(srcp[e], __float_as_int(lat[e]));
    }
}

// ---------------------------------------------------------------------------
// k_qkvr: batched GEMV via fp16 dot2 (fp32 accum). Weights in LDS as half2
// d-pairs (~37 KB -> 4 blocks/CU; grid 1024 exposes it). BN fused into
// x-staging. Outputs FP16: Q (128h), interleaved KV (256h), R (128h).
// ---------------------------------------------------------------------------
__global__ __launch_bounds__(512, 4) void k_qkvr(
        const float* __restrict__ xin, const float* __restrict__ nt,
        const float* __restrict__ rq, int din, int N,
        const float* __restrict__ Wq, const float* __restrict__ bq,
        const float* __restrict__ Wk, const float* __restrict__ bk,
        const float* __restrict__ Wv, const float* __restrict__ bv,
        const float* __restrict__ Ws, const float* __restrict__ bs,
        const double* __restrict__ SUM, const double* __restrict__ SUMSQ,
        const float* __restrict__ bng, const float* __restrict__ bnb,
        int applyBN,
        __half* __restrict__ Q, __half* __restrict__ KV, __half* __restrict__ R) {
    __shared__ h2 w2[4][16 * 128];     // 32 KB max
    __shared__ float bias[4][128];
    __shared__ h2 xs2[32][17];
    __shared__ float sscale[32], sshift[32];
    int t = threadIdx.x;
    int dpCount = din >> 1;            // 16 or 1
    for (int i = t; i < dpCount * 128; i += 512) {
        int dp = i >> 7, j = i & 127;
        w2[0][i] = f2h2(Wq[(size_t)(2 * dp) * 128 + j], Wq[(size_t)(2 * dp + 1) * 128 + j]);
        w2[1][i] = f2h2(Wk[(size_t)(2 * dp) * 128 + j], Wk[(size_t)(2 * dp + 1) * 128 + j]);
        w2[2][i] = f2h2(Wv[(size_t)(2 * dp) * 128 + j], Wv[(size_t)(2 * dp + 1) * 128 + j]);
        w2[3][i] = f2h2(Ws[(size_t)(2 * dp) * 128 + j], Ws[(size_t)(2 * dp + 1) * 128 + j]);
    }
    if (t < 128) {
        bias[0][t] = bq[t]; bias[1][t] = bk[t]; bias[2][t] = bv[t]; bias[3][t] = bs[t];
    }
    if (t < 32) {
        if (applyBN) {
            double m = SUM[t] / N;
            double v = SUMSQ[t] / N - m * m;
            float inv = rsqrtf((float)v + 1e-5f);
            float sc = inv * bng[t];
            sscale[t] = sc;
            sshift[t] = bnb[t] - (float)m * sc;
        } else {
            sscale[t] = 1.f; sshift[t] = 0.f;
        }
    }
    int quad = t & 31;
    int sub = t >> 5;   // 0..15, two nodes each
    int dpsh = (din == 32) ? 4 : 0;
    int tiles = (N + 31) >> 5;
    for (int tile = blockIdx.x; tile < tiles; tile += gridDim.x) {
        int base = tile << 5;
        __syncthreads();
        for (int i = t; i < 32 * dpCount; i += 512) {
            int nl = i >> dpsh, dp = i & (dpCount - 1);
            int nn = base + nl;
            float x0 = 0.f, x1 = 0.f;
            if (nn < N) {
                if (din == 2) { x0 = nt[nn]; x1 = rq[nn]; }
                else {
                    x0 = xin[(size_t)nn * din + 2 * dp];
                    x1 = xin[(size_t)nn * din + 2 * dp + 1];
                }
            }
            x0 = x0 * sscale[2 * dp] + sshift[2 * dp];
            x1 = x1 * sscale[2 * dp + 1] + sshift[2 * dp + 1];
            xs2[nl][dp] = f2h2(x0, x1);
        }
        __syncthreads();
        float acc[4][2][4];  // [mat][node][comp]
#pragma unroll
        for (int m = 0; m < 4; ++m)
#pragma unroll
            for (int k = 0; k < 2; ++k)
#pragma unroll
                for (int c = 0; c < 4; ++c) acc[m][k][c] = bias[m][quad * 4 + c];
        for (int dp = 0; dp < dpCount; ++dp) {
            h2 xv0 = xs2[sub * 2 + 0][dp];
            h2 xv1 = xs2[sub * 2 + 1][dp];
#pragma unroll
            for (int m = 0; m < 4; ++m) {
                const h2* wp = &w2[m][dp * 128 + quad * 4];
                h2 wa = wp[0], wb = wp[1], wc = wp[2], wd = wp[3];
                acc[m][0][0] = fdot2f(xv0, wa, acc[m][0][0]);
                acc[m][0][1] = fdot2f(xv0, wb, acc[m][0][1]);
                acc[m][0][2] = fdot2f(xv0, wc, acc[m][0][2]);
                acc[m][0][3] = fdot2f(xv0, wd, acc[m][0][3]);
                acc[m][1][0] = fdot2f(xv1, wa, acc[m][1][0]);
                acc[m][1][1] = fdot2f(xv1, wb, acc[m][1][1]);
                acc[m][1][2] = fdot2f(xv1, wc, acc[m][1][2]);
                acc[m][1][3] = fdot2f(xv1, wd, acc[m][1][3]);
            }
        }
#pragma unroll
        for (int k = 0; k < 2; ++k) {
            int n = base + sub * 2 + k;
            if (n < N) {
                *(__half2*)&Q[(size_t)n * 128 + quad * 4 + 0] =
                    __floats2half2_rn(acc[0][k][0], acc[0][k][1]);
                *(__half2*)&Q[(size_t)n * 128 + quad * 4 + 2] =
                    __floats2half2_rn(acc[0][k][2], acc[0][k][3]);
                *(__half2*)&KV[(size_t)n * 256 + quad * 4 + 0] =
                    __floats2half2_rn(acc[1][k][0], acc[1][k][1]);
                *(__half2*)&KV[(size_t)n * 256 + quad * 4 + 2] =
                    __floats2half2_rn(acc[1][k][2], acc[1][k][3]);
                *(__half2*)&KV[(size_t)n * 256 + 128 + quad * 4 + 0] =
                    __floats2half2_rn(acc[2][k][0], acc[2][k][1]);
                *(__half2*)&KV[(size_t)n * 256 + 128 + quad * 4 + 2] =
                    __floats2half2_rn(acc[2][k][2], acc[2][k][3]);
                *(__half2*)&R[(size_t)n * 128 + quad * 4 + 0] =
                    __floats2half2_rn(acc[3][k][0], acc[3][k][1]);
                *(__half2*)&R[(size_t)n * 128 + quad * 4 + 2] =
                    __floats2half2_rn(acc[3][k][2], acc[3][k][3]);
            }
        }
    }
}

// ---------------------------------------------------------------------------
// k_attn: PURE attention. 2 nodes x 2 slots x 16 lanes per wave (R7 winner).
// ---------------------------------------------------------------------------
__global__ __launch_bounds__(256) void k_attn(
        const int2* __restrict__ srclat,
        const __half* __restrict__ Q, const __half* __restrict__ KV,
        const float* __restrict__ We,
        const __half* __restrict__ R, const float* __restrict__ Wb,
        const int* __restrict__ rowptr, const int* __restrict__ deg,
        __half* __restrict__ A, int N) {
    __shared__ float weL[128], wboL[128], wbrL[128];
    int t = threadIdx.x;
    if (t < 128) {
        float w0 = Wb[t], w1 = Wb[128 + t], w2v = Wb[256 + t];
        weL[t] = We[t];
        wboL[t] = w0 + w2v;
        wbrL[t] = w1 - w2v;
    }
    __syncthreads();

    int wvid = t >> 6;
    int l64 = t & 63;
    int slot = (l64 >> 4) & 1;  // 0..1: 2 edges per node per iteration
    int nsub = l64 >> 5;        // 0..1: which node this lane serves
    int lane = l64 & 15;        // 16 lanes x 8 halfs = 128 channels
    const f32x2* wep = (const f32x2*)&weL[lane * 8];
    const f32x2* bop = (const f32x2*)&wboL[lane * 8];
    const f32x2* brp = (const f32x2*)&wbrL[lane * 8];
    h2 weh0, weh1, weh2, weh3;
    {
        f32x2 wa = wep[0], wb = wep[1], wc = wep[2], wd = wep[3];
        weh0 = f2h2(wa.x, wa.y); weh1 = f2h2(wb.x, wb.y);
        weh2 = f2h2(wc.x, wc.y); weh3 = f2h2(wd.x, wd.y);
    }
    const float4 f4z = make_float4(0.f, 0.f, 0.f, 0.f);

    int T = gridDim.x * 4;      // waves
    int T2 = T * 2;             // nodes per sweep
    int base0 = (blockIdx.x * 4 + wvid) * 2;   // wave-uniform first node

    f4h qh, rh, k0, v0;
    int start = 0, d = 0; float l0 = 0.f;
    f4h pq, pr, pk, pv;
    float pl = 0.f;
    int s1 = 0, d1 = 0;
    int2 psl1 = make_int2(0, 0);
    int s2 = 0, d2 = 0;
    qh.f = f4z; rh.f = f4z; k0.f = f4z; v0.f = f4z;
    pq.f = f4z; pr.f = f4z; pk.f = f4z; pv.f = f4z;

    {
        int n0l = base0 + nsub;
        if (n0l < N) {
            start = rowptr[n0l]; d = deg[n0l];
            qh.f = *(const float4*)(Q + (size_t)n0l * 128 + lane * 8);
            rh.f = *(const float4*)(R + (size_t)n0l * 128 + lane * 8);
            if (slot < d) {
                int2 sl = srclat[start + slot];
                l0 = __int_as_float(sl.y);
                k0.f = *(const float4*)(KV + (size_t)sl.x * 256 + lane * 8);
                v0.f = *(const float4*)(KV + (size_t)sl.x * 256 + 128 + lane * 8);
            }
            int n1l = n0l + T2;
            if (n1l < N) {
                s1 = rowptr[n1l]; d1 = deg[n1l];
                if (slot < d1) psl1 = srclat[s1 + slot];
            }
            int n2l = n0l + 2 * T2;
            if (n2l < N) { s2 = rowptr[n2l]; d2 = deg[n2l]; }
        }
    }

    for (int nb = base0; nb < N; nb += T2) {
        int n = nb + nsub;
        int n1 = n + T2, n2 = n + 2 * T2, n3 = n + 3 * T2;
        int s3 = 0, d3 = 0;
        if (n3 < N) { s3 = rowptr[n3]; d3 = deg[n3]; }
        int2 psl2 = make_int2(0, 0);
        if (n2 < N && slot < d2) psl2 = srclat[s2 + slot];
        if (n1 < N) {
            pq.f = *(const float4*)(Q + (size_t)n1 * 128 + lane * 8);
            pr.f = *(const float4*)(R + (size_t)n1 * 128 + lane * 8);
            if (slot < d1) {
                pl = __int_as_float(psl1.y);
                pk.f = *(const float4*)(KV + (size_t)psl1.x * 256 + lane * 8);
                pv.f = *(const float4*)(KV + (size_t)psl1.x * 256 + 128 + lane * 8);
            }
        }

        float qwe = fdot2f(qh.h[0], weh0, fdot2f(qh.h[1], weh1,
                    fdot2f(qh.h[2], weh2, fdot2f(qh.h[3], weh3, 0.f))));
        qwe += __shfl_xor(qwe, 1); qwe += __shfl_xor(qwe, 2);

        float m = -INFINITY, den = 0.f, plsum = 0.f;
        f32x2 A0 = bc2(0.f), A1 = bc2(0.f), A2 = bc2(0.f), A3 = bc2(0.f);

        int idx = slot;
        bool have = idx < d;
        while (have) {
            int idx2 = idx + 2;
            bool have2 = idx2 < d;
            float l1 = 0.f;
            f4h k1, v1;
            if (have2) {
                int2 sl = srclat[start + idx2];
                l1 = __int_as_float(sl.y);
                k1.f = *(const float4*)(KV + (size_t)sl.x * 256 + lane * 8);
                v1.f = *(const float4*)(KV + (size_t)sl.x * 256 + 128 + lane * 8);
            }

            float t0 = fdot2f(qh.h[0], k0.h[0], fdot2f(qh.h[1], k0.h[1],
                       fdot2f(qh.h[2], k0.h[2], fdot2f(qh.h[3], k0.h[3], 0.f))));
            t0 += __shfl_xor(t0, 1); t0 += __shfl_xor(t0, 2);
            float alpha = fmaf(l0, qwe, t0) * 0.17677669529663687f;

            float mn = fmaxf(m, alpha);
            float sc = __expf(m - mn);
            float p = __expf(alpha - mn);
            f32x2 sc2 = bc2(sc), p2 = bc2(p);
            A0 = A0 * sc2 + p2 * cvt2(v0.h[0]);
            A1 = A1 * sc2 + p2 * cvt2(v0.h[1]);
            A2 = A2 * sc2 + p2 * cvt2(v0.h[2]);
            A3 = A3 * sc2 + p2 * cvt2(v0.h[3]);
            plsum = plsum * sc + p * l0;
            den = fmaf(den, sc, p);
            m = mn;

            idx = idx2; l0 = l1;
            k0.f = k1.f; v0.f = v1.f;
            have = have2;
        }

        // combine the 2 slots (xor 16 stays within this node's 32 lanes)
        {
            float mo = __shfl_xor(m, 16);
            float mn = fmaxf(m, mo);
            float sc = (m == -INFINITY) ? 0.f : __expf(m - mn);
            f32x2 sc2 = bc2(sc);
            A0 *= sc2; A1 *= sc2; A2 *= sc2; A3 *= sc2;
            den *= sc; plsum *= sc;
            A0 += mk2(__shfl_xor(A0.x, 16), __shfl_xor(A0.y, 16));
            A1 += mk2(__shfl_xor(A1.x, 16), __shfl_xor(A1.y, 16));
            A2 += mk2(__shfl_xor(A2.x, 16), __shfl_xor(A2.y, 16));
            A3 += mk2(__shfl_xor(A3.x, 16), __shfl_xor(A3.y, 16));
            den += __shfl_xor(den, 16); plsum += __shfl_xor(plsum, 16);
            m = mn;
        }

        float inv = 1.f / (den + 1e-16f);
        f32x2 inv2 = bc2(inv), pls2 = bc2(plsum);
        f32x2 O0 = (A0 + pls2 * wep[0]) * inv2;
        f32x2 O1 = (A1 + pls2 * wep[1]) * inv2;
        f32x2 O2 = (A2 + pls2 * wep[2]) * inv2;
        f32x2 O3 = (A3 + pls2 * wep[3]) * inv2;

        f32x2 R0 = cvt2(rh.h[0]), R1 = cvt2(rh.h[1]);
        f32x2 R2 = cvt2(rh.h[2]), R3 = cvt2(rh.h[3]);
        f32x2 G = O0 * bop[0];
        G += R0 * brp[0];
        G += O1 * bop[1]; G += R1 * brp[1];
        G += O2 * bop[2]; G += R2 * brp[2];
        G += O3 * bop[3]; G += R3 * brp[3];
        float g = G.x + G.y;
        g += __shfl_xor(g, 1); g += __shfl_xor(g, 2);
        g += __shfl_xor(g, 4); g += __shfl_xor(g, 8);
        float beta = 1.0f / (1.0f + __expf(-g));

        if ((l64 & 16) == 0 && n < N) {
            f32x2 bb = bc2(beta), ib = bc2(1.0f - beta);
            f32x2 W0 = bb * R0 + ib * O0;
            f32x2 W1 = bb * R1 + ib * O1;
            f32x2 W2 = bb * R2 + ib * O2;
            f32x2 W3 = bb * R3 + ib * O3;
            *(__half2*)&A[(size_t)n * 128 + lane * 8 + 0] = __floats2half2_rn(W0.x, W0.y);
            *(__half2*)&A[(size_t)n * 128 + lane * 8 + 2] = __floats2half2_rn(W1.x, W1.y);
            *(__half2*)&A[(size_t)n * 128 + lane * 8 + 4] = __floats2half2_rn(W2.x, W2.y);
            *(__half2*)&A[(size_t)n * 128 + lane * 8 + 6] = __floats2half2_rn(W3.x, W3.y);
        }

        qh.f = pq.f; rh.f = pr.f; k0.f = pk.f; v0.f = pv.f; l0 = pl;
        start = s1; d = d1;
        s1 = s2; d1 = d2; s2 = s3; d2 = d3;
        psl1 = psl2;
    }
}

// ---------------------------------------------------------------------------
// k_linstats: Y = relu(A(fp16) @ tW + tb) via fp16 dot2 (unchanged).
// ---------------------------------------------------------------------------
__global__ __launch_bounds__(256) void k_linstats(
        const __half* __restrict__ A, const float* __restrict__ tW,
        const float* __restrict__ tb, float* __restrict__ H32,
        double* __restrict__ partials, int N) {
    __shared__ h2 w2l[64 * 32];       // 8 KB
    __shared__ float bias[32];
    __shared__ h2 xsT[64][66];        // ~16.9 KB, dp-major
    __shared__ double sp1[4][8][4], sp2[4][8][4];
    int t = threadIdx.x;
    for (int i = t; i < 64 * 32; i += 256) {
        int dp = i >> 5, j = i & 31;
        w2l[i] = f2h2(tW[(size_t)(2 * dp) * 32 + j], tW[(size_t)(2 * dp + 1) * 32 + j]);
    }
    if (t < 32) bias[t] = tb[t];
    int quad = t & 7;
    int sub = t >> 3;
    int base = blockIdx.x << 6;

    __syncthreads();
#pragma unroll
    for (int k = 0; k < 4; ++k) {
        int i = t + 256 * k;
        int nl = i >> 4, g8 = i & 15;
        int n = base + nl;
        h2 hv[4];
        if (n < N) {
            const h2* ap = (const h2*)(A + (size_t)n * 128 + g8 * 8);
            hv[0] = ap[0]; hv[1] = ap[1]; hv[2] = ap[2]; hv[3] = ap[3];
        } else {
            h2 z; z.x = (_Float16)0.f; z.y = (_Float16)0.f;
            hv[0] = z; hv[1] = z; hv[2] = z; hv[3] = z;
        }
        xsT[g8 * 4 + 0][nl] = hv[0];
        xsT[g8 * 4 + 1][nl] = hv[1];
        xsT[g8 * 4 + 2][nl] = hv[2];
        xsT[g8 * 4 + 3][nl] = hv[3];
    }
    __syncthreads();

    float acc[2][4];
#pragma unroll
    for (int k = 0; k < 2; ++k)
#pragma unroll
        for (int c = 0; c < 4; ++c) acc[k][c] = bias[quad * 4 + c];
    for (int dp = 0; dp < 64; ++dp) {
        h2 x0 = xsT[dp][sub * 2 + 0];
        h2 x1 = xsT[dp][sub * 2 + 1];
        const h2* wp = &w2l[dp * 32 + quad * 4];
        h2 wa = wp[0], wb = wp[1], wc = wp[2], wd = wp[3];
        acc[0][0] = fdot2f(x0, wa, acc[0][0]);
        acc[0][1] = fdot2f(x0, wb, acc[0][1]);
        acc[0][2] = fdot2f(x0, wc, acc[0][2]);
        acc[0][3] = fdot2f(x0, wd, acc[0][3]);
        acc[1][0] = fdot2f(x1, wa, acc[1][0]);
        acc[1][1] = fdot2f(x1, wb, acc[1][1]);
        acc[1][2] = fdot2f(x1, wc, acc[1][2]);
        acc[1][3] = fdot2f(x1, wd, acc[1][3]);
    }
    double s1[4] = {0, 0, 0, 0}, s2[4] = {0, 0, 0, 0};
#pragma unroll
    for (int k = 0; k < 2; ++k) {
        int n = base + sub * 2 + k;
        if (n < N) {
            float4 yv;
            yv.x = fmaxf(acc[k][0], 0.f); yv.y = fmaxf(acc[k][1], 0.f);
            yv.z = fmaxf(acc[k][2], 0.f); yv.w = fmaxf(acc[k][3], 0.f);
            *(float4*)&H32[(size_t)n * 32 + quad * 4] = yv;
            s1[0] += yv.x; s1[1] += yv.y; s1[2] += yv.z; s1[3] += yv.w;
            s2[0] += (double)yv.x * yv.x; s2[1] += (double)yv.y * yv.y;
            s2[2] += (double)yv.z * yv.z; s2[3] += (double)yv.w * yv.w;
        }
    }
    // reduce over subs within each wave (quad preserved under xor >= 8)
#pragma unroll
    for (int c = 0; c < 4; ++c) {
        s1[c] += __shfl_xor(s1[c], 8);  s2[c] += __shfl_xor(s2[c], 8);
        s1[c] += __shfl_xor(s1[c], 16); s2[c] += __shfl_xor(s2[c], 16);
        s1[c] += __shfl_xor(s1[c], 32); s2[c] += __shfl_xor(s2[c], 32);
    }
    __syncthreads();
    int wave = t >> 6;
    if ((t & 63) < 8) {
#pragma unroll
        for (int c = 0; c < 4; ++c) { sp1[wave][quad][c] = s1[c]; sp2[wave][quad][c] = s2[c]; }
    }
    __syncthreads();
    if (t < 32) {
        int q = t >> 2, c = t & 3;
        double a1 = 0, a2 = 0;
#pragma unroll
        for (int wv = 0; wv < 4; ++wv) { a1 += sp1[wv][q][c]; a2 += sp2[wv][q][c]; }
        partials[(size_t)blockIdx.x * 64 + t] = a1;
        partials[(size_t)blockIdx.x * 64 + 32 + t] = a2;
    }
}

// ---------------------------------------------------------------------------
// Single-kernel stat reduction: block = one output column (64 blocks).
// ---------------------------------------------------------------------------
__global__ void k_statred(const double* __restrict__ partials,
                          double* __restrict__ SUM, double* __restrict__ SUMSQ,
                          int nblocks) {
    __shared__ double s[256];
    int col = blockIdx.x;   // 0..63
    double a = 0;
    for (int b = threadIdx.x; b < nblocks; b += 256)
        a += partials[(size_t)b * 64 + col];
    s[threadIdx.x] = a;
    __syncthreads();
    for (int st = 128; st > 0; st >>= 1) {
        if (threadIdx.x < st) s[threadIdx.x] += s[threadIdx.x + st];
        __syncthreads();
    }
    if (threadIdx.x == 0) {
        if (col < 32) SUM[col] = s[0];
        else SUMSQ[col - 32] = s[0];
    }
}

// ---------------------------------------------------------------------------
// k_mlp12: FUSED BN affine + 32->128 relu + 128->64 relu. Y1 lives in LDS
// (16-node tiles). ~59.5 KB LDS -> 2 blocks/CU. Block 0 zero-inits head
// scratch (slot1/slot2/a1buf).
// ---------------------------------------------------------------------------
__global__ __launch_bounds__(256) void k_mlp12(
        const float* __restrict__ H32,
        const double* __restrict__ SUM, const double* __restrict__ SUMSQ,
        const float* __restrict__ bng, const float* __restrict__ bnb,
        const float* __restrict__ W1, const float* __restrict__ b1,
        const float* __restrict__ W2, const float* __restrict__ b2,
        float* __restrict__ Y2, unsigned int* __restrict__ smallbuf, int N) {
    __shared__ float w1[32 * 128];     // 16 KB
    __shared__ float sb1[128];
    __shared__ float sscale[32], sshift[32];
    __shared__ float w2f[128 * 64];    // 32 KB
    __shared__ float sb2[64];
    __shared__ float xs[16][36];       // 2.25 KB
    __shared__ float y1[16][132];      // 8.25 KB
    int t = threadIdx.x;
    if (blockIdx.x == 0 && t < 16) smallbuf[t] = 0u;  // zero 64 B head scratch
    for (int i = t; i < 32 * 128; i += 256) w1[i] = W1[i];
    for (int i = t; i < 128 * 64; i += 256) w2f[i] = W2[i];
    if (t < 128) sb1[t] = b1[t];
    if (t < 64) sb2[t] = b2[t];
    if (t < 32) {
        double m = SUM[t] / N;
        double v = SUMSQ[t] / N - m * m;
        float inv = rsqrtf((float)v + 1e-5f);
        float sc = inv * bng[t];
        sscale[t] = sc;
        sshift[t] = bnb[t] - (float)m * sc;
    }
    int q1 = t & 31, s1_ = t >> 5;     // phase1: 32 quads x 4 cols, 8 subs x 2 nodes
    int q2 = t & 15, s2_ = t >> 4;     // phase2: 16 quads x 4 cols, 16 nodes
    int tiles = (N + 15) >> 4;
    for (int tile = blockIdx.x; tile < tiles; tile += gridDim.x) {
        int base = tile << 4;
        __syncthreads();
        if (t < 128) {
            int nl = t >> 3, q = t & 7;
            int n = base + nl;
            float4 xv = make_float4(0.f, 0.f, 0.f, 0.f);
            if (n < N) xv = *(const float4*)&H32[(size_t)n * 32 + q * 4];
            xs[nl][q * 4 + 0] = xv.x * sscale[q * 4 + 0] + sshift[q * 4 + 0];
            xs[nl][q * 4 + 1] = xv.y * sscale[q * 4 + 1] + sshift[q * 4 + 1];
            xs[nl][q * 4 + 2] = xv.z * sscale[q * 4 + 2] + sshift[q * 4 + 2];
            xs[nl][q * 4 + 3] = xv.w * sscale[q * 4 + 3] + sshift[q * 4 + 3];
        }
        __syncthreads();
        // phase1: 32 -> 128, relu into y1 LDS
        float a[2][4];
#pragma unroll
        for (int k = 0; k < 2; ++k)
#pragma unroll
            for (int c = 0; c < 4; ++c) a[k][c] = sb1[q1 * 4 + c];
        for (int d = 0; d < 32; ++d) {
            float4 w4 = *(const float4*)&w1[d * 128 + q1 * 4];
#pragma unroll
            for (int k = 0; k < 2; ++k) {
                float x = xs[s1_ * 2 + k][d];
                a[k][0] = fmaf(x, w4.x, a[k][0]);
                a[k][1] = fmaf(x, w4.y, a[k][1]);
                a[k][2] = fmaf(x, w4.z, a[k][2]);
                a[k][3] = fmaf(x, w4.w, a[k][3]);
            }
        }
#pragma unroll
        for (int k = 0; k < 2; ++k) {
            float4 yv;
            yv.x = fmaxf(a[k][0], 0.f); yv.y = fmaxf(a[k][1], 0.f);
            yv.z = fmaxf(a[k][2], 0.f); yv.w = fmaxf(a[k][3], 0.f);
            *(float4*)&y1[s1_ * 2 + k][q1 * 4] = yv;
        }
        __syncthreads();
        // phase2: 128 -> 64, relu to global
        float b[4];
#pragma unroll
        for (int c = 0; c < 4; ++c) b[c] = sb2[q2 * 4 + c];
        for (int d = 0; d < 128; ++d) {
            float4 w4 = *(const float4*)&w2f[d * 64 + q2 * 4];
            float x = y1[s2_][d];
            b[0] = fmaf(x, w4.x, b[0]);
            b[1] = fmaf(x, w4.y, b[1]);
            b[2] = fmaf(x, w4.z, b[2]);
            b[3] = fmaf(x, w4.w, b[3]);
        }
        int n = base + s2_;
        if (n < N) {
            float4 yv;
            yv.x = fmaxf(b[0], 0.f); yv.y = fmaxf(b[1], 0.f);
            yv.z = fmaxf(b[2], 0.f); yv.w = fmaxf(b[3], 0.f);
            *(float4*)&Y2[(size_t)n * 64 + q2 * 4] = yv;
        }
    }
}

// ---------------------------------------------------------------------------
// k_mlp3h: 64->64 GEMV (X3) FUSED with head1: logits1 = X3@remW + remB +
// mask, written to l1out; per-block online logsumexp partials (float2) and
// per-block gumbel-argmax (one atomicMax per block). Plain launch bounds:
// needs ~184 VGPR; capping it spills to scratch (R11: 600 MB, 4x slower).
// ---------------------------------------------------------------------------
__global__ __launch_bounds__(256) void k_mlp3h(
        const float* __restrict__ Y2, const float* __restrict__ W3,
        const float* __restrict__ b3,
        const float* __restrict__ remW, const float* __restrict__ remB,
        const int* __restrict__ active,
        float* __restrict__ X3, float* __restrict__ l1out,
        unsigned long long* __restrict__ slot1, float2* __restrict__ part1,
        int N) {
    __shared__ float w3[64 * 64];
    __shared__ float sb3[64];
    __shared__ float xs[32][68];
    __shared__ float srw[64];
    __shared__ float redm[256], reds[256];
    __shared__ unsigned long long redb[256];
    int t = threadIdx.x;
    for (int i = t; i < 64 * 64; i += 256) w3[i] = W3[i];
    if (t < 64) { sb3[t] = b3[t]; srw[t] = remW[t]; }
    float rB = remB[0];
    int quad = t & 15, sub = t >> 4;
    float lm = -INFINITY, ls = 0.f;
    unsigned long long best = 0ull;
    int tiles = (N + 31) >> 5;
    for (int tile = blockIdx.x; tile < tiles; tile += gridDim.x) {
        int base = tile << 5;
        __syncthreads();
#pragma unroll
        for (int k = 0; k < 2; ++k) {
            int i = t + 256 * k;
            int nl = i >> 4, q = i & 15;
            int n = base + nl;
            float4 xv = make_float4(0.f, 0.f, 0.f, 0.f);
            if (n < N) xv = *(const float4*)&Y2[(size_t)n * 64 + q * 4];
            *(float4*)&xs[nl][q * 4] = xv;
        }
        __syncthreads();
        float a[2][4];
#pragma unroll
        for (int k = 0; k < 2; ++k)
#pragma unroll
            for (int c = 0; c < 4; ++c) a[k][c] = sb3[quad * 4 + c];
        for (int d = 0; d < 64; ++d) {
            float4 w4 = *(const float4*)&w3[d * 64 + quad * 4];
#pragma unroll
            for (int k = 0; k < 2; ++k) {
                float x = xs[sub * 2 + k][d];
                a[k][0] = fmaf(x, w4.x, a[k][0]);
                a[k][1] = fmaf(x, w4.y, a[k][1]);
                a[k][2] = fmaf(x, w4.z, a[k][2]);
                a[k][3] = fmaf(x, w4.w, a[k][3]);
            }
        }
#pragma unroll
        for (int k = 0; k < 2; ++k) {
            int n = base + sub * 2 + k;
            if (n < N)
                *(float4*)&X3[(size_t)n * 64 + quad * 4] = *(float4*)a[k];
        }
        // fused head1: per-node dot with remW via 16-lane butterfly
#pragma unroll
        for (int k = 0; k < 2; ++k) {
            int n = base + sub * 2 + k;
            float h = a[k][0] * srw[quad * 4 + 0] + a[k][1] * srw[quad * 4 + 1]
                    + a[k][2] * srw[quad * 4 + 2] + a[k][3] * srw[quad * 4 + 3];
            h += __shfl_xor(h, 1); h += __shfl_xor(h, 2);
            h += __shfl_xor(h, 4); h += __shfl_xor(h, 8);
            if (quad == 0 && n < N) {
                float maskf = (active[n] == 1) ? 0.f : NEGF;
                float rm_ = (n < 15) ? ((maskf == 0.f) ? NEGF : 0.f) : maskf;
                float l1 = h + rB + rm_;
                l1out[n] = l1;
                lse_merge(lm, ls, l1, 1.0f);
                float z = l1 + gumbel_at(n, 0, N);
                unsigned long long p = ((unsigned long long)fmono(z) << 32) |
                                       (unsigned long long)(0xFFFFFFFFu - (unsigned)n);
                if (p > best) best = p;
            }
        }
    }
    // block reduce (m,s) + best
    redm[t] = lm; reds[t] = ls; redb[t] = best;
    __syncthreads();
    for (int st = 128; st > 0; st >>= 1) {
        if (t < st) {
            float m2 = redm[t + st], s2 = reds[t + st];
            float mm = redm[t], ss = reds[t];
            lse_merge(mm, ss, m2, s2);
            redm[t] = mm; reds[t] = ss;
            if (redb[t + st] > redb[t]) redb[t] = redb[t + st];
        }
        __syncthreads();
    }
    if (t == 0) {
        part1[blockIdx.x] = make_float2(redm[0], reds[0]);
        if (redb[0]) atomicMax(slot1, redb[0]);
    }
}

// ---------------------------------------------------------------------------
// Head kernels
// ---------------------------------------------------------------------------
__global__ void k_head2(const float* __restrict__ X3, const float* __restrict__ addW,
                        const float* __restrict__ addB,
                        const unsigned long long* __restrict__ slot1,
                        float* __restrict__ tvec, int* __restrict__ a1buf) {
    int j = threadIdx.x;  // 64
    unsigned long long p = *slot1;
    int a1 = (int)(0xFFFFFFFFu - (unsigned)(p & 0xFFFFFFFFull));
    const float* xr = X3 + (size_t)a1 * 64;
    float acc = addB[j];
    for (int d = 0; d < 64; d++) acc = fmaf(xr[d], addW[d * 64 + j], acc);
    tvec[j] = tanhf(acc);
    if (j == 0) *a1buf = a1;
}

// head3 with per-block logsumexp partials + per-block argmax atomic.
__global__ void k_head3p(const float* __restrict__ X3, const float* __restrict__ tvec,
                         const int* __restrict__ active, const int* __restrict__ a1buf,
                         float* __restrict__ l2out, unsigned long long* __restrict__ slot2,
                         float2* __restrict__ part2, int N) {
    __shared__ float redm[256], reds[256];
    __shared__ unsigned long long redb[256];
    int t = threadIdx.x;
    int n = blockIdx.x * 256 + t;
    float lm = -INFINITY, ls = 0.f;
    unsigned long long best = 0ull;
    if (n < N) {
        const float* xr = X3 + (size_t)n * 64;
        float acc = 0.f;
        for (int d = 0; d < 64; d++) acc = fmaf(xr[d], tvec[d], acc);
        float maskf = (active[n] == 1) ? 0.f : NEGF;
        if (n == *a1buf) maskf = 0.f;
        float l2 = acc + maskf;
        l2out[n] = l2;
        lm = l2; ls = 1.f;
        float z = l2 + gumbel_at(n, 1, N);
        best = ((unsigned long long)fmono(z) << 32) |
               (unsigned long long)(0xFFFFFFFFu - (unsigned)n);
    }
    redm[t] = lm; reds[t] = ls; redb[t] = best;
    __syncthreads();
    for (int st = 128; st > 0; st >>= 1) {
        if (t < st) {
            float mm = redm[t], ss = reds[t];
            lse_merge(mm, ss, redm[t + st], reds[t + st]);
            redm[t] = mm; reds[t] = ss;
            if (redb[t + st] > redb[t]) redb[t] = redb[t + st];
        }
        __syncthreads();
    }
    if (t == 0) {
        part2[blockIdx.x] = make_float2(redm[0], reds[0]);
        if (redb[0]) atomicMax(slot2, redb[0]);
    }
}

__global__ void k_final2(const float* __restrict__ l1, const float* __restrict__ l2,
                         const unsigned long long* __restrict__ slot2,
                         const int* __restrict__ a1buf,
                         const float2* __restrict__ part1, int np1,
                         const float2* __restrict__ part2, int np2,
                         float* __restrict__ outTail) {
    __shared__ float rm[256], rs[256];
    int t = threadIdx.x;
    // reduce part1
    float m = -INFINITY, s = 0.f;
    for (int i = t; i < np1; i += 256) { float2 p = part1[i]; lse_merge(m, s, p.x, p.y); }
    rm[t] = m; rs[t] = s;
    __syncthreads();
    for (int st = 128; st > 0; st >>= 1) {
        if (t < st) { float mm = rm[t], ss = rs[t]; lse_merge(mm, ss, rm[t + st], rs[t + st]); rm[t] = mm; rs[t] = ss; }
        __syncthreads();
    }
    float M1 = rm[0], S1 = rs[0];
    __syncthreads();
    // reduce part2
    m = -INFINITY; s = 0.f;
    for (int i = t; i < np2; i += 256) { float2 p = part2[i]; lse_merge(m, s, p.x, p.y); }
    rm[t] = m; rs[t] = s;
    __syncthreads();
    for (int st = 128; st > 0; st >>= 1) {
        if (t < st) { float mm = rm[t], ss = rs[t]; lse_merge(mm, ss, rm[t + st], rs[t + st]); rm[t] = mm; rs[t] = ss; }
        __syncthreads();
    }
    float M2 = rm[0], S2 = rs[0];
    if (t == 0) {
        int a1 = *a1buf;
        int a2 = (int)(0xFFFFFFFFu - (unsigned)((*slot2) & 0xFFFFFFFFull));
        outTail[0] = (float)a1;
        outTail[1] = (float)a2;
        outTail[2] = l1[a1] - (M1 + logf(S1));
        outTail[3] = l2[a2] - (M2 + logf(S2));
    }
}

// ---------------------------------------------------------------------------
// Host launcher
// ---------------------------------------------------------------------------
extern "C" void kernel_launch(void* const* d_in, const int* in_sizes, int n_in,
                              void* d_out, int out_size, void* d_ws, size_t ws_size,
                              hipStream_t stream) {
    const float* node_type = (const float*)d_in[0];
    const float* requests  = (const float*)d_in[1];
    const float* latency   = (const float*)d_in[2];
    const int* edge_index  = (const int*)d_in[3];
    const int* active      = (const int*)d_in[4];
    int N = in_sizes[0];
    int E = in_sizes[2];
    const int* src = edge_index;
    const int* dst = edge_index + E;
    float* out = (float*)d_out;

    char* base = (char*)d_ws;
    size_t off = 0;
    auto alloc = [&](size_t bytes) -> char* {
        char* p = base + off;
        off += (bytes + 255) & ~(size_t)255;
        return p;
    };
    char* Abuf   = alloc((size_t)N * 128 * 4);  // fp16 A; later fp32 Y2
    char* Qbuf   = alloc((size_t)N * 128 * 4);  // fp16 Q
    __half* KV   = (__half*)alloc((size_t)N * 256 * 2); // interleaved K,V fp16
    char* Rbuf   = alloc((size_t)N * 128 * 4);  // fp16 R; later fp32 X3
    float* H32   = (float*)alloc((size_t)N * 32 * 4);
    int* deg     = (int*)alloc((size_t)N * 4);
    int* rowptr  = (int*)alloc((size_t)N * 4);
    int* cursor  = (int*)alloc((size_t)N * 4);
    int2* srclat = (int2*)alloc((size_t)E * 8);
    int* bsum    = (int*)alloc(1024 * 4);
    int lsTiles = (N + 63) / 64;
    double* partials = (double*)alloc((size_t)lsTiles * 64 * 8);
    double* SUM  = (double*)alloc(512);
    double* SUMSQ = SUM + 32;
    float2* part1 = (float2*)alloc(521 * 8);
    int ng = (N + 255) / 256;
    float2* part2 = (float2*)alloc((size_t)ng * 8);
    char* small  = alloc(1024);
    unsigned long long* slot1 = (unsigned long long*)small;
    unsigned long long* slot2 = slot1 + 1;
    int* a1buf = (int*)(small + 32);
    float* tvec = (float*)(small + 64);

    __half* Ah = (__half*)Abuf;   float* Y2f = (float*)Abuf;
    __half* Qh = (__half*)Qbuf;
    __half* Rh = (__half*)Rbuf;   float* X3f = (float*)Rbuf;

    int egE = (E + 255) / 256;
    int nb = ng;

    // ---- CSR build ----
    (void)hipMemsetAsync(deg, 0, (size_t)N * 4, stream);
    k_hist<<<egE, 256, 0, stream>>>(dst, deg, E);
    k_scan1<<<nb, 256, 0, stream>>>(deg, bsum, N);
    k_scan2<<<1, 256, 0, stream>>>(bsum, nb);
    k_scan3<<<nb, 256, 0, stream>>>(deg, bsum, rowptr, cursor, N);
    k_fill<<<egE, 256, 0, stream>>>(dst, src, latency, cursor, srclat, E);

    for (int L = 0; L < 5; ++L) {
        int din = L ? 32 : 2;
        const float* xin = L ? H32 : nullptr;
        const float* Wq = L ? (const float*)d_in[19] + (size_t)(L - 1) * 4096 : (const float*)d_in[5];
        const float* bq = L ? (const float*)d_in[20] + (size_t)(L - 1) * 128  : (const float*)d_in[6];
        const float* Wk = L ? (const float*)d_in[21] + (size_t)(L - 1) * 4096 : (const float*)d_in[7];
        const float* bk = L ? (const float*)d_in[22] + (size_t)(L - 1) * 128  : (const float*)d_in[8];
        const float* Wv = L ? (const float*)d_in[23] + (size_t)(L - 1) * 4096 : (const float*)d_in[9];
        const float* bv = L ? (const float*)d_in[24] + (size_t)(L - 1) * 128  : (const float*)d_in[10];
        const float* We = L ? (const float*)d_in[25] + (size_t)(L - 1) * 128  : (const float*)d_in[11];
        const float* Ws = L ? (const float*)d_in[26] + (size_t)(L - 1) * 4096 : (const float*)d_in[12];
        const float* bs = L ? (const float*)d_in[27] + (size_t)(L - 1) * 128  : (const float*)d_in[13];
        const float* Wb = L ? (const float*)d_in[28] + (size_t)(L - 1) * 384  : (const float*)d_in[14];
        const float* tW = L ? (const float*)d_in[29] + (size_t)(L - 1) * 4096 : (const float*)d_in[15];
        const float* tb = L ? (const float*)d_in[30] + (size_t)(L - 1) * 32   : (const float*)d_in[16];
        const float* bngP = (L == 1) ? (const float*)d_in[17]
                          : (L >= 2) ? (const float*)d_in[31] + (size_t)(L - 2) * 32 : nullptr;
        const float* bnbP = (L == 1) ? (const float*)d_in[18]
                          : (L >= 2) ? (const float*)d_in[32] + (size_t)(L - 2) * 32 : nullptr;

        k_qkvr<<<1024, 512, 0, stream>>>(xin, node_type, requests, din, N,
                                         Wq, bq, Wk, bk, Wv, bv, Ws, bs,
                                         SUM, SUMSQ, bngP, bnbP, (L > 0) ? 1 : 0,
                                         Qh, KV, Rh);
        k_attn<<<ATTNGRID, 256, 0, stream>>>(srclat, Qh, KV, We, Rh, Wb,
                                             rowptr, deg, Ah, N);
        k_linstats<<<lsTiles, 256, 0, stream>>>(Ah, tW, tb, H32, partials, N);
        k_statred<<<64, 256, 0, stream>>>(partials, SUM, SUMSQ, lsTiles);
    }

    // embedding MLP: H32 -> (Y1 in LDS) -> Y2(Abuf) -> X3(Rbuf) + fused head1
    k_mlp12<<<512, 256, 0, stream>>>(H32, SUM, SUMSQ,
                                     (const float*)d_in[31] + 3 * 32,
                                     (const float*)d_in[32] + 3 * 32,
                                     (const float*)d_in[33], (const float*)d_in[34],
                                     (const float*)d_in[35], (const float*)d_in[36],
                                     Y2f, (unsigned int*)small, N);
    k_mlp3h<<<521, 256, 0, stream>>>(Y2f, (const float*)d_in[37], (const float*)d_in[38],
                                     (const float*)d_in[39], (const float*)d_in[40],
                                     active, X3f, out, slot1, part1, N);
    k_head2<<<1, 64, 0, stream>>>(X3f, (const float*)d_in[41], (const float*)d_in[42],
                                  slot1, tvec, a1buf);
    k_head3p<<<ng, 256, 0, stream>>>(X3f, tvec, active, a1buf, out + N, slot2,
                                     part2, N);
    k_final2<<<1, 256, 0, stream>>>(out, out + N, slot2, a1buf,
                                    part1, 521, part2, ng, out + 2 * N);
}

// Round 13
// 674.023 us; speedup vs baseline: 1.2696x; 1.0152x over previous
//
#include <hip/hip_runtime.h>
#include <hip/hip_fp16.h>
#include <cstdint>
#include <math.h>

typedef _Float16 h2 __attribute__((ext_vector_type(2)));
typedef float f32x2 __attribute__((ext_vector_type(2)));

__device__ __forceinline__ h2 f2h2(float a, float b) {
    h2 r; r.x = (_Float16)a; r.y = (_Float16)b; return r;
}
__device__ __forceinline__ float fdot2f(h2 a, h2 b, float c) {
    return __builtin_amdgcn_fdot2(a, b, c, false);
}
__device__ __forceinline__ f32x2 bc2(float x) { f32x2 r; r.x = x; r.y = x; return r; }
__device__ __forceinline__ f32x2 cvt2(h2 v) {
    f32x2 r; r.x = (float)v.x; r.y = (float)v.y; return r;
}
__device__ __forceinline__ f32x2 mk2(float a, float b) { f32x2 r; r.x = a; r.y = b; return r; }

// 16-byte-aligned fragment: 8 halfs, loadable as one float4.
union f4h {
    float4 f;
    h2 h[4];
    __half2 u[4];
};

// ---------------------------------------------------------------------------
// Threefry-2x32-20, exactly as JAX lowers it.
// ---------------------------------------------------------------------------
__device__ __forceinline__ uint32_t rotl32(uint32_t x, uint32_t n) {
    return (x << n) | (x >> (32u - n));
}

__device__ __forceinline__ void tf2x32(uint32_t k0, uint32_t k1,
                                       uint32_t x0, uint32_t x1,
                                       uint32_t& o0, uint32_t& o1) {
    uint32_t k2 = k0 ^ k1 ^ 0x1BD11BDAu;
    x0 += k0; x1 += k1;
    x0 += x1; x1 = rotl32(x1, 13); x1 ^= x0;
    x0 += x1; x1 = rotl32(x1, 15); x1 ^= x0;
    x0 += x1; x1 = rotl32(x1, 26); x1 ^= x0;
    x0 += x1; x1 = rotl32(x1, 6);  x1 ^= x0;
    x0 += k1; x1 += k2 + 1u;
    x0 += x1; x1 = rotl32(x1, 17); x1 ^= x0;
    x0 += x1; x1 = rotl32(x1, 29); x1 ^= x0;
    x0 += x1; x1 = rotl32(x1, 16); x1 ^= x0;
    x0 += x1; x1 = rotl32(x1, 24); x1 ^= x0;
    x0 += k2; x1 += k0 + 2u;
    x0 += x1; x1 = rotl32(x1, 13); x1 ^= x0;
    x0 += x1; x1 = rotl32(x1, 15); x1 ^= x0;
    x0 += x1; x1 = rotl32(x1, 26); x1 ^= x0;
    x0 += x1; x1 = rotl32(x1, 6);  x1 ^= x0;
    x0 += k0; x1 += k1 + 3u;
    x0 += x1; x1 = rotl32(x1, 17); x1 ^= x0;
    x0 += x1; x1 = rotl32(x1, 29); x1 ^= x0;
    x0 += x1; x1 = rotl32(x1, 16); x1 ^= x0;
    x0 += x1; x1 = rotl32(x1, 24); x1 ^= x0;
    x0 += k1; x1 += k2 + 4u;
    x0 += x1; x1 = rotl32(x1, 13); x1 ^= x0;
    x0 += x1; x1 = rotl32(x1, 15); x1 ^= x0;
    x0 += x1; x1 = rotl32(x1, 26); x1 ^= x0;
    x0 += x1; x1 = rotl32(x1, 6);  x1 ^= x0;
    x0 += k2; x1 += k0 + 5u;
    o0 = x0; o1 = x1;
}

__device__ float gumbel_at(int n, int which, int N) {
    uint32_t a0, a1, b0, b1;
    tf2x32(0u, 42u, 0u, 2u, a0, a1);   // constant-folded by compiler
    tf2x32(0u, 42u, 1u, 3u, b0, b1);
    uint32_t gk0 = which ? a1 : a0;
    uint32_t gk1 = which ? b1 : b0;
    int half = N >> 1;
    uint32_t o0, o1, bits;
    if (n < half) { tf2x32(gk0, gk1, (uint32_t)n, (uint32_t)(n + half), o0, o1); bits = o0; }
    else          { tf2x32(gk0, gk1, (uint32_t)(n - half), (uint32_t)n, o0, o1); bits = o1; }
    float f = __uint_as_float((bits >> 9) | 0x3F800000u) - 1.0f;
    float u = fmaxf(1.17549435e-38f, f);
    return -logf(-logf(u));
}

__device__ __forceinline__ uint32_t fmono(float f) {
    uint32_t b = __float_as_uint(f);
    return (b & 0x80000000u) ? ~b : (b | 0x80000000u);
}
__device__ __forceinline__ float funmono(uint32_t u) {
    uint32_t b = (u & 0x80000000u) ? (u & 0x7FFFFFFFu) : ~u;
    return __uint_as_float(b);
}

// online logsumexp merge: (m,s) <- merge((m,s),(m2,s2))
__device__ __forceinline__ void lse_merge(float& m, float& s, float m2, float s2) {
    float M = fmaxf(m, m2);
    float a = (m == -INFINITY) ? 0.f : expf(m - M) * s;
    float b = (m2 == -INFINITY) ? 0.f : expf(m2 - M) * s2;
    m = M; s = a + b;
}

#define NEGF (-1e9f)
#define ATTNGRID 2048  /* persistent attn blocks */

// ---------------------------------------------------------------------------
// CSR build
// ---------------------------------------------------------------------------
__global__ void k_hist(const int* __restrict__ dstp, int* __restrict__ deg, int E) {
    int e = blockIdx.x * 256 + threadIdx.x;
    if (e < E) atomicAdd(&deg[dstp[e]], 1);
}

__global__ void k_scan1(const int* __restrict__ deg, int* __restrict__ bsum, int N) {
    __shared__ int s[256];
    int i = blockIdx.x * 256 + threadIdx.x;
    s[threadIdx.x] = (i < N) ? deg[i] : 0;
    __syncthreads();
    for (int st = 128; st > 0; st >>= 1) {
        if (threadIdx.x < st) s[threadIdx.x] += s[threadIdx.x + st];
        __syncthreads();
    }
    if (threadIdx.x == 0) bsum[blockIdx.x] = s[0];
}

__global__ void k_scan2(int* __restrict__ bsum, int nb) {
    __shared__ int s[256];
    int i = threadIdx.x;
    int v = (i < nb) ? bsum[i] : 0;
    s[i] = v;
    __syncthreads();
    for (int st = 1; st < 256; st <<= 1) {
        int t = (i >= st) ? s[i - st] : 0;
        __syncthreads();
        s[i] += t;
        __syncthreads();
    }
    if (i < nb) bsum[i] = s[i] - v;  // exclusive
}

__global__ void k_scan3(const int* __restrict__ deg, const int* __restrict__ bsum,
                        int* __restrict__ rowptr, int* __restrict__ cursor, int N) {
    __shared__ int s[256];
    int i = blockIdx.x * 256 + threadIdx.x;
    int v = (i < N) ? deg[i] : 0;
    s[threadIdx.x] = v;
    __syncthreads();
    for (int st = 1; st < 256; st <<= 1) {
        int t = (threadIdx.x >= st) ? s[threadIdx.x - st] : 0;
        __syncthreads();
        s[threadIdx.x] += t;
        __syncthreads();
    }
    int excl = s[threadIdx.x] - v + bsum[blockIdx.x];
    if (i < N) { rowptr[i] = excl; cursor[i] = excl; }
}

__global__ void k_fill(const int* __restrict__ dstp, const int* __restrict__ srcp,
                       const float* __restrict__ lat, int* __restrict__ cursor,
                       int2* __restrict__ srclat, int E) {
    int e = blockIdx.x * 256 + threadIdx.x;
    if (e < E) {
        int pos = atomicAdd(&cursor[dstp[e]], 1);
        srclat[pos] = make_int2(srcp[e], __float_as_int(lat[e]));
    }
}

// ---------------------------------------------------------------------------
// k_qkvr: batched GEMV via fp16 dot2 (fp32 accum). Weights in LDS as half2
// d-pairs (~37 KB -> 4 blocks/CU; grid 1024 exposes it). BN fused into
// x-staging. Outputs FP16: Q (128h), interleaved KV (256h), R (128h).
// ---------------------------------------------------------------------------
__global__ __launch_bounds__(512, 4) void k_qkvr(
        const float* __restrict__ xin, const float* __restrict__ nt,
        const float* __restrict__ rq, int din, int N,
        const float* __restrict__ Wq, const float* __restrict__ bq,
        const float* __restrict__ Wk, const float* __restrict__ bk,
        const float* __restrict__ Wv, const float* __restrict__ bv,
        const float* __restrict__ Ws, const float* __restrict__ bs,
        const double* __restrict__ SUM, const double* __restrict__ SUMSQ,
        const float* __restrict__ bng, const float* __restrict__ bnb,
        int applyBN,
        __half* __restrict__ Q, __half* __restrict__ KV, __half* __restrict__ R) {
    __shared__ h2 w2[4][16 * 128];     // 32 KB max
    __shared__ float bias[4][128];
    __shared__ h2 xs2[32][17];
    __shared__ float sscale[32], sshift[32];
    int t = threadIdx.x;
    int dpCount = din >> 1;            // 16 or 1
    for (int i = t; i < dpCount * 128; i += 512) {
        int dp = i >> 7, j = i & 127;
        w2[0][i] = f2h2(Wq[(size_t)(2 * dp) * 128 + j], Wq[(size_t)(2 * dp + 1) * 128 + j]);
        w2[1][i] = f2h2(Wk[(size_t)(2 * dp) * 128 + j], Wk[(size_t)(2 * dp + 1) * 128 + j]);
        w2[2][i] = f2h2(Wv[(size_t)(2 * dp) * 128 + j], Wv[(size_t)(2 * dp + 1) * 128 + j]);
        w2[3][i] = f2h2(Ws[(size_t)(2 * dp) * 128 + j], Ws[(size_t)(2 * dp + 1) * 128 + j]);
    }
    if (t < 128) {
        bias[0][t] = bq[t]; bias[1][t] = bk[t]; bias[2][t] = bv[t]; bias[3][t] = bs[t];
    }
    if (t < 32) {
        if (applyBN) {
            double m = SUM[t] / N;
            double v = SUMSQ[t] / N - m * m;
            float inv = rsqrtf((float)v + 1e-5f);
            float sc = inv * bng[t];
            sscale[t] = sc;
            sshift[t] = bnb[t] - (float)m * sc;
        } else {
            sscale[t] = 1.f; sshift[t] = 0.f;
        }
    }
    int quad = t & 31;
    int sub = t >> 5;   // 0..15, two nodes each
    int dpsh = (din == 32) ? 4 : 0;
    int tiles = (N + 31) >> 5;
    for (int tile = blockIdx.x; tile < tiles; tile += gridDim.x) {
        int base = tile << 5;
        __syncthreads();
        for (int i = t; i < 32 * dpCount; i += 512) {
            int nl = i >> dpsh, dp = i & (dpCount - 1);
            int nn = base + nl;
            float x0 = 0.f, x1 = 0.f;
            if (nn < N) {
                if (din == 2) { x0 = nt[nn]; x1 = rq[nn]; }
                else {
                    x0 = xin[(size_t)nn * din + 2 * dp];
                    x1 = xin[(size_t)nn * din + 2 * dp + 1];
                }
            }
            x0 = x0 * sscale[2 * dp] + sshift[2 * dp];
            x1 = x1 * sscale[2 * dp + 1] + sshift[2 * dp + 1];
            xs2[nl][dp] = f2h2(x0, x1);
        }
        __syncthreads();
        float acc[4][2][4];  // [mat][node][comp]
#pragma unroll
        for (int m = 0; m < 4; ++m)
#pragma unroll
            for (int k = 0; k < 2; ++k)
#pragma unroll
                for (int c = 0; c < 4; ++c) acc[m][k][c] = bias[m][quad * 4 + c];
        for (int dp = 0; dp < dpCount; ++dp) {
            h2 xv0 = xs2[sub * 2 + 0][dp];
            h2 xv1 = xs2[sub * 2 + 1][dp];
#pragma unroll
            for (int m = 0; m < 4; ++m) {
                const h2* wp = &w2[m][dp * 128 + quad * 4];
                h2 wa = wp[0], wb = wp[1], wc = wp[2], wd = wp[3];
                acc[m][0][0] = fdot2f(xv0, wa, acc[m][0][0]);
                acc[m][0][1] = fdot2f(xv0, wb, acc[m][0][1]);
                acc[m][0][2] = fdot2f(xv0, wc, acc[m][0][2]);
                acc[m][0][3] = fdot2f(xv0, wd, acc[m][0][3]);
                acc[m][1][0] = fdot2f(xv1, wa, acc[m][1][0]);
                acc[m][1][1] = fdot2f(xv1, wb, acc[m][1][1]);
                acc[m][1][2] = fdot2f(xv1, wc, acc[m][1][2]);
                acc[m][1][3] = fdot2f(xv1, wd, acc[m][1][3]);
            }
        }
#pragma unroll
        for (int k = 0; k < 2; ++k) {
            int n = base + sub * 2 + k;
            if (n < N) {
                *(__half2*)&Q[(size_t)n * 128 + quad * 4 + 0] =
                    __floats2half2_rn(acc[0][k][0], acc[0][k][1]);
                *(__half2*)&Q[(size_t)n * 128 + quad * 4 + 2] =
                    __floats2half2_rn(acc[0][k][2], acc[0][k][3]);
                *(__half2*)&KV[(size_t)n * 256 + quad * 4 + 0] =
                    __floats2half2_rn(acc[1][k][0], acc[1][k][1]);
                *(__half2*)&KV[(size_t)n * 256 + quad * 4 + 2] =
                    __floats2half2_rn(acc[1][k][2], acc[1][k][3]);
                *(__half2*)&KV[(size_t)n * 256 + 128 + quad * 4 + 0] =
                    __floats2half2_rn(acc[2][k][0], acc[2][k][1]);
                *(__half2*)&KV[(size_t)n * 256 + 128 + quad * 4 + 2] =
                    __floats2half2_rn(acc[2][k][2], acc[2][k][3]);
                *(__half2*)&R[(size_t)n * 128 + quad * 4 + 0] =
                    __floats2half2_rn(acc[3][k][0], acc[3][k][1]);
                *(__half2*)&R[(size_t)n * 128 + quad * 4 + 2] =
                    __floats2half2_rn(acc[3][k][2], acc[3][k][3]);
            }
        }
    }
}

// ---------------------------------------------------------------------------
// k_attn: PURE attention. 2 nodes x 2 slots x 16 lanes per wave (R7 winner).
// ---------------------------------------------------------------------------
__global__ __launch_bounds__(256) void k_attn(
        const int2* __restrict__ srclat,
        const __half* __restrict__ Q, const __half* __restrict__ KV,
        const float* __restrict__ We,
        const __half* __restrict__ R, const float* __restrict__ Wb,
        const int* __restrict__ rowptr, const int* __restrict__ deg,
        __half* __restrict__ A, int N) {
    __shared__ float weL[128], wboL[128], wbrL[128];
    int t = threadIdx.x;
    if (t < 128) {
        float w0 = Wb[t], w1 = Wb[128 + t], w2v = Wb[256 + t];
        weL[t] = We[t];
        wboL[t] = w0 + w2v;
        wbrL[t] = w1 - w2v;
    }
    __syncthreads();

    int wvid = t >> 6;
    int l64 = t & 63;
    int slot = (l64 >> 4) & 1;  // 0..1: 2 edges per node per iteration
    int nsub = l64 >> 5;        // 0..1: which node this lane serves
    int lane = l64 & 15;        // 16 lanes x 8 halfs = 128 channels
    const f32x2* wep = (const f32x2*)&weL[lane * 8];
    const f32x2* bop = (const f32x2*)&wboL[lane * 8];
    const f32x2* brp = (const f32x2*)&wbrL[lane * 8];
    h2 weh0, weh1, weh2, weh3;
    {
        f32x2 wa = wep[0], wb = wep[1], wc = wep[2], wd = wep[3];
        weh0 = f2h2(wa.x, wa.y); weh1 = f2h2(wb.x, wb.y);
        weh2 = f2h2(wc.x, wc.y); weh3 = f2h2(wd.x, wd.y);
    }
    const float4 f4z = make_float4(0.f, 0.f, 0.f, 0.f);

    int T = gridDim.x * 4;      // waves
    int T2 = T * 2;             // nodes per sweep
    int base0 = (blockIdx.x * 4 + wvid) * 2;   // wave-uniform first node

    f4h qh, rh, k0, v0;
    int start = 0, d = 0; float l0 = 0.f;
    f4h pq, pr, pk, pv;
    float pl = 0.f;
    int s1 = 0, d1 = 0;
    int2 psl1 = make_int2(0, 0);
    int s2 = 0, d2 = 0;
    qh.f = f4z; rh.f = f4z; k0.f = f4z; v0.f = f4z;
    pq.f = f4z; pr.f = f4z; pk.f = f4z; pv.f = f4z;

    {
        int n0l = base0 + nsub;
        if (n0l < N) {
            start = rowptr[n0l]; d = deg[n0l];
            qh.f = *(const float4*)(Q + (size_t)n0l * 128 + lane * 8);
            rh.f = *(const float4*)(R + (size_t)n0l * 128 + lane * 8);
            if (slot < d) {
                int2 sl = srclat[start + slot];
                l0 = __int_as_float(sl.y);
                k0.f = *(const float4*)(KV + (size_t)sl.x * 256 + lane * 8);
                v0.f = *(const float4*)(KV + (size_t)sl.x * 256 + 128 + lane * 8);
            }
            int n1l = n0l + T2;
            if (n1l < N) {
                s1 = rowptr[n1l]; d1 = deg[n1l];
                if (slot < d1) psl1 = srclat[s1 + slot];
            }
            int n2l = n0l + 2 * T2;
            if (n2l < N) { s2 = rowptr[n2l]; d2 = deg[n2l]; }
        }
    }

    for (int nb = base0; nb < N; nb += T2) {
        int n = nb + nsub;
        int n1 = n + T2, n2 = n + 2 * T2, n3 = n + 3 * T2;
        int s3 = 0, d3 = 0;
        if (n3 < N) { s3 = rowptr[n3]; d3 = deg[n3]; }
        int2 psl2 = make_int2(0, 0);
        if (n2 < N && slot < d2) psl2 = srclat[s2 + slot];
        if (n1 < N) {
            pq.f = *(const float4*)(Q + (size_t)n1 * 128 + lane * 8);
            pr.f = *(const float4*)(R + (size_t)n1 * 128 + lane * 8);
            if (slot < d1) {
                pl = __int_as_float(psl1.y);
                pk.f = *(const float4*)(KV + (size_t)psl1.x * 256 + lane * 8);
                pv.f = *(const float4*)(KV + (size_t)psl1.x * 256 + 128 + lane * 8);
            }
        }

        float qwe = fdot2f(qh.h[0], weh0, fdot2f(qh.h[1], weh1,
                    fdot2f(qh.h[2], weh2, fdot2f(qh.h[3], weh3, 0.f))));
        qwe += __shfl_xor(qwe, 1); qwe += __shfl_xor(qwe, 2);

        float m = -INFINITY, den = 0.f, plsum = 0.f;
        f32x2 A0 = bc2(0.f), A1 = bc2(0.f), A2 = bc2(0.f), A3 = bc2(0.f);

        int idx = slot;
        bool have = idx < d;
        while (have) {
            int idx2 = idx + 2;
            bool have2 = idx2 < d;
            float l1 = 0.f;
            f4h k1, v1;
            if (have2) {
                int2 sl = srclat[start + idx2];
                l1 = __int_as_float(sl.y);
                k1.f = *(const float4*)(KV + (size_t)sl.x * 256 + lane * 8);
                v1.f = *(const float4*)(KV + (size_t)sl.x * 256 + 128 + lane * 8);
            }

            float t0 = fdot2f(qh.h[0], k0.h[0], fdot2f(qh.h[1], k0.h[1],
                       fdot2f(qh.h[2], k0.h[2], fdot2f(qh.h[3], k0.h[3], 0.f))));
            t0 += __shfl_xor(t0, 1); t0 += __shfl_xor(t0, 2);
            float alpha = fmaf(l0, qwe, t0) * 0.17677669529663687f;

            float mn = fmaxf(m, alpha);
            float sc = __expf(m - mn);
            float p = __expf(alpha - mn);
            f32x2 sc2 = bc2(sc), p2 = bc2(p);
            A0 = A0 * sc2 + p2 * cvt2(v0.h[0]);
            A1 = A1 * sc2 + p2 * cvt2(v0.h[1]);
            A2 = A2 * sc2 + p2 * cvt2(v0.h[2]);
            A3 = A3 * sc2 + p2 * cvt2(v0.h[3]);
            plsum = plsum * sc + p * l0;
            den = fmaf(den, sc, p);
            m = mn;

            idx = idx2; l0 = l1;
            k0.f = k1.f; v0.f = v1.f;
            have = have2;
        }

        // combine the 2 slots (xor 16 stays within this node's 32 lanes)
        {
            float mo = __shfl_xor(m, 16);
            float mn = fmaxf(m, mo);
            float sc = (m == -INFINITY) ? 0.f : __expf(m - mn);
            f32x2 sc2 = bc2(sc);
            A0 *= sc2; A1 *= sc2; A2 *= sc2; A3 *= sc2;
            den *= sc; plsum *= sc;
            A0 += mk2(__shfl_xor(A0.x, 16), __shfl_xor(A0.y, 16));
            A1 += mk2(__shfl_xor(A1.x, 16), __shfl_xor(A1.y, 16));
            A2 += mk2(__shfl_xor(A2.x, 16), __shfl_xor(A2.y, 16));
            A3 += mk2(__shfl_xor(A3.x, 16), __shfl_xor(A3.y, 16));
            den += __shfl_xor(den, 16); plsum += __shfl_xor(plsum, 16);
            m = mn;
        }

        float inv = 1.f / (den + 1e-16f);
        f32x2 inv2 = bc2(inv), pls2 = bc2(plsum);
        f32x2 O0 = (A0 + pls2 * wep[0]) * inv2;
        f32x2 O1 = (A1 + pls2 * wep[1]) * inv2;
        f32x2 O2 = (A2 + pls2 * wep[2]) * inv2;
        f32x2 O3 = (A3 + pls2 * wep[3]) * inv2;

        f32x2 R0 = cvt2(rh.h[0]), R1 = cvt2(rh.h[1]);
        f32x2 R2 = cvt2(rh.h[2]), R3 = cvt2(rh.h[3]);
        f32x2 G = O0 * bop[0];
        G += R0 * brp[0];
        G += O1 * bop[1]; G += R1 * brp[1];
        G += O2 * bop[2]; G += R2 * brp[2];
        G += O3 * bop[3]; G += R3 * brp[3];
        float g = G.x + G.y;
        g += __shfl_xor(g, 1); g += __shfl_xor(g, 2);
        g += __shfl_xor(g, 4); g += __shfl_xor(g, 8);
        float beta = 1.0f / (1.0f + __expf(-g));

        if ((l64 & 16) == 0 && n < N) {
            f32x2 bb = bc2(beta), ib = bc2(1.0f - beta);
            f32x2 W0 = bb * R0 + ib * O0;
            f32x2 W1 = bb * R1 + ib * O1;
            f32x2 W2 = bb * R2 + ib * O2;
            f32x2 W3 = bb * R3 + ib * O3;
            *(__half2*)&A[(size_t)n * 128 + lane * 8 + 0] = __floats2half2_rn(W0.x, W0.y);
            *(__half2*)&A[(size_t)n * 128 + lane * 8 + 2] = __floats2half2_rn(W1.x, W1.y);
            *(__half2*)&A[(size_t)n * 128 + lane * 8 + 4] = __floats2half2_rn(W2.x, W2.y);
            *(__half2*)&A[(size_t)n * 128 + lane * 8 + 6] = __floats2half2_rn(W3.x, W3.y);
        }

        qh.f = pq.f; rh.f = pr.f; k0.f = pk.f; v0.f = pv.f; l0 = pl;
        start = s1; d = d1;
        s1 = s2; d1 = d2; s2 = s3; d2 = d3;
        psl1 = psl2;
    }
}

// ---------------------------------------------------------------------------
// k_linstats: Y = relu(A(fp16) @ tW + tb) via fp16 dot2 (unchanged).
// ---------------------------------------------------------------------------
__global__ __launch_bounds__(256) void k_linstats(
        const __half* __restrict__ A, const float* __restrict__ tW,
        const float* __restrict__ tb, float* __restrict__ H32,
        double* __restrict__ partials, int N) {
    __shared__ h2 w2l[64 * 32];       // 8 KB
    __shared__ float bias[32];
    __shared__ h2 xsT[64][66];        // ~16.9 KB, dp-major
    __shared__ double sp1[4][8][4], sp2[4][8][4];
    int t = threadIdx.x;
    for (int i = t; i < 64 * 32; i += 256) {
        int dp = i >> 5, j = i & 31;
        w2l[i] = f2h2(tW[(size_t)(2 * dp) * 32 + j], tW[(size_t)(2 * dp + 1) * 32 + j]);
    }
    if (t < 32) bias[t] = tb[t];
    int quad = t & 7;
    int sub = t >> 3;
    int base = blockIdx.x << 6;

    __syncthreads();
#pragma unroll
    for (int k = 0; k < 4; ++k) {
        int i = t + 256 * k;
        int nl = i >> 4, g8 = i & 15;
        int n = base + nl;
        h2 hv[4];
        if (n < N) {
            const h2* ap = (const h2*)(A + (size_t)n * 128 + g8 * 8);
            hv[0] = ap[0]; hv[1] = ap[1]; hv[2] = ap[2]; hv[3] = ap[3];
        } else {
            h2 z; z.x = (_Float16)0.f; z.y = (_Float16)0.f;
            hv[0] = z; hv[1] = z; hv[2] = z; hv[3] = z;
        }
        xsT[g8 * 4 + 0][nl] = hv[0];
        xsT[g8 * 4 + 1][nl] = hv[1];
        xsT[g8 * 4 + 2][nl] = hv[2];
        xsT[g8 * 4 + 3][nl] = hv[3];
    }
    __syncthreads();

    float acc[2][4];
#pragma unroll
    for (int k = 0; k < 2; ++k)
#pragma unroll
        for (int c = 0; c < 4; ++c) acc[k][c] = bias[quad * 4 + c];
    for (int dp = 0; dp < 64; ++dp) {
        h2 x0 = xsT[dp][sub * 2 + 0];
        h2 x1 = xsT[dp][sub * 2 + 1];
        const h2* wp = &w2l[dp * 32 + quad * 4];
        h2 wa = wp[0], wb = wp[1], wc = wp[2], wd = wp[3];
        acc[0][0] = fdot2f(x0, wa, acc[0][0]);
        acc[0][1] = fdot2f(x0, wb, acc[0][1]);
        acc[0][2] = fdot2f(x0, wc, acc[0][2]);
        acc[0][3] = fdot2f(x0, wd, acc[0][3]);
        acc[1][0] = fdot2f(x1, wa, acc[1][0]);
        acc[1][1] = fdot2f(x1, wb, acc[1][1]);
        acc[1][2] = fdot2f(x1, wc, acc[1][2]);
        acc[1][3] = fdot2f(x1, wd, acc[1][3]);
    }
    double s1[4] = {0, 0, 0, 0}, s2[4] = {0, 0, 0, 0};
#pragma unroll
    for (int k = 0; k < 2; ++k) {
        int n = base + sub * 2 + k;
        if (n < N) {
            float4 yv;
            yv.x = fmaxf(acc[k][0], 0.f); yv.y = fmaxf(acc[k][1], 0.f);
            yv.z = fmaxf(acc[k][2], 0.f); yv.w = fmaxf(acc[k][3], 0.f);
            *(float4*)&H32[(size_t)n * 32 + quad * 4] = yv;
            s1[0] += yv.x; s1[1] += yv.y; s1[2] += yv.z; s1[3] += yv.w;
            s2[0] += (double)yv.x * yv.x; s2[1] += (double)yv.y * yv.y;
            s2[2] += (double)yv.z * yv.z; s2[3] += (double)yv.w * yv.w;
        }
    }
    // reduce over subs within each wave (quad preserved under xor >= 8)
#pragma unroll
    for (int c = 0; c < 4; ++c) {
        s1[c] += __shfl_xor(s1[c], 8);  s2[c] += __shfl_xor(s2[c], 8);
        s1[c] += __shfl_xor(s1[c], 16); s2[c] += __shfl_xor(s2[c], 16);
        s1[c] += __shfl_xor(s1[c], 32); s2[c] += __shfl_xor(s2[c], 32);
    }
    __syncthreads();
    int wave = t >> 6;
    if ((t & 63) < 8) {
#pragma unroll
        for (int c = 0; c < 4; ++c) { sp1[wave][quad][c] = s1[c]; sp2[wave][quad][c] = s2[c]; }
    }
    __syncthreads();
    if (t < 32) {
        int q = t >> 2, c = t & 3;
        double a1 = 0, a2 = 0;
#pragma unroll
        for (int wv = 0; wv < 4; ++wv) { a1 += sp1[wv][q][c]; a2 += sp2[wv][q][c]; }
        partials[(size_t)blockIdx.x * 64 + t] = a1;
        partials[(size_t)blockIdx.x * 64 + 32 + t] = a2;
    }
}

// ---------------------------------------------------------------------------
// Single-kernel stat reduction: block = one output column (64 blocks).
// ---------------------------------------------------------------------------
__global__ void k_statred(const double* __restrict__ partials,
                          double* __restrict__ SUM, double* __restrict__ SUMSQ,
                          int nblocks) {
    __shared__ double s[256];
    int col = blockIdx.x;   // 0..63
    double a = 0;
    for (int b = threadIdx.x; b < nblocks; b += 256)
        a += partials[(size_t)b * 64 + col];
    s[threadIdx.x] = a;
    __syncthreads();
    for (int st = 128; st > 0; st >>= 1) {
        if (threadIdx.x < st) s[threadIdx.x] += s[threadIdx.x + st];
        __syncthreads();
    }
    if (threadIdx.x == 0) {
        if (col < 32) SUM[col] = s[0];
        else SUMSQ[col - 32] = s[0];
    }
}

// ---------------------------------------------------------------------------
// k_mlp12: FUSED BN affine + 32->128 relu + 128->64 relu. Y1 lives in LDS
// (16-node tiles). ~59.5 KB LDS -> 2 blocks/CU. Block 0 zero-inits head
// scratch (slot1/slot2/a1buf).
// ---------------------------------------------------------------------------
__global__ __launch_bounds__(256) void k_mlp12(
        const float* __restrict__ H32,
        const double* __restrict__ SUM, const double* __restrict__ SUMSQ,
        const float* __restrict__ bng, const float* __restrict__ bnb,
        const float* __restrict__ W1, const float* __restrict__ b1,
        const float* __restrict__ W2, const float* __restrict__ b2,
        float* __restrict__ Y2, unsigned int* __restrict__ smallbuf, int N) {
    __shared__ float w1[32 * 128];     // 16 KB
    __shared__ float sb1[128];
    __shared__ float sscale[32], sshift[32];
    __shared__ float w2f[128 * 64];    // 32 KB
    __shared__ float sb2[64];
    __shared__ float xs[16][36];       // 2.25 KB
    __shared__ float y1[16][132];      // 8.25 KB
    int t = threadIdx.x;
    if (blockIdx.x == 0 && t < 16) smallbuf[t] = 0u;  // zero 64 B head scratch
    for (int i = t; i < 32 * 128; i += 256) w1[i] = W1[i];
    for (int i = t; i < 128 * 64; i += 256) w2f[i] = W2[i];
    if (t < 128) sb1[t] = b1[t];
    if (t < 64) sb2[t] = b2[t];
    if (t < 32) {
        double m = SUM[t] / N;
        double v = SUMSQ[t] / N - m * m;
        float inv = rsqrtf((float)v + 1e-5f);
        float sc = inv * bng[t];
        sscale[t] = sc;
        sshift[t] = bnb[t] - (float)m * sc;
    }
    int q1 = t & 31, s1_ = t >> 5;     // phase1: 32 quads x 4 cols, 8 subs x 2 nodes
    int q2 = t & 15, s2_ = t >> 4;     // phase2: 16 quads x 4 cols, 16 nodes
    int tiles = (N + 15) >> 4;
    for (int tile = blockIdx.x; tile < tiles; tile += gridDim.x) {
        int base = tile << 4;
        __syncthreads();
        if (t < 128) {
            int nl = t >> 3, q = t & 7;
            int n = base + nl;
            float4 xv = make_float4(0.f, 0.f, 0.f, 0.f);
            if (n < N) xv = *(const float4*)&H32[(size_t)n * 32 + q * 4];
            xs[nl][q * 4 + 0] = xv.x * sscale[q * 4 + 0] + sshift[q * 4 + 0];
            xs[nl][q * 4 + 1] = xv.y * sscale[q * 4 + 1] + sshift[q * 4 + 1];
            xs[nl][q * 4 + 2] = xv.z * sscale[q * 4 + 2] + sshift[q * 4 + 2];
            xs[nl][q * 4 + 3] = xv.w * sscale[q * 4 + 3] + sshift[q * 4 + 3];
        }
        __syncthreads();
        // phase1: 32 -> 128, relu into y1 LDS
        float a[2][4];
#pragma unroll
        for (int k = 0; k < 2; ++k)
#pragma unroll
            for (int c = 0; c < 4; ++c) a[k][c] = sb1[q1 * 4 + c];
        for (int d = 0; d < 32; ++d) {
            float4 w4 = *(const float4*)&w1[d * 128 + q1 * 4];
#pragma unroll
            for (int k = 0; k < 2; ++k) {
                float x = xs[s1_ * 2 + k][d];
                a[k][0] = fmaf(x, w4.x, a[k][0]);
                a[k][1] = fmaf(x, w4.y, a[k][1]);
                a[k][2] = fmaf(x, w4.z, a[k][2]);
                a[k][3] = fmaf(x, w4.w, a[k][3]);
            }
        }
#pragma unroll
        for (int k = 0; k < 2; ++k) {
            float4 yv;
            yv.x = fmaxf(a[k][0], 0.f); yv.y = fmaxf(a[k][1], 0.f);
            yv.z = fmaxf(a[k][2], 0.f); yv.w = fmaxf(a[k][3], 0.f);
            *(float4*)&y1[s1_ * 2 + k][q1 * 4] = yv;
        }
        __syncthreads();
        // phase2: 128 -> 64, relu to global
        float b[4];
#pragma unroll
        for (int c = 0; c < 4; ++c) b[c] = sb2[q2 * 4 + c];
        for (int d = 0; d < 128; ++d) {
            float4 w4 = *(const float4*)&w2f[d * 64 + q2 * 4];
            float x = y1[s2_][d];
            b[0] = fmaf(x, w4.x, b[0]);
            b[1] = fmaf(x, w4.y, b[1]);
            b[2] = fmaf(x, w4.z, b[2]);
            b[3] = fmaf(x, w4.w, b[3]);
        }
        int n = base + s2_;
        if (n < N) {
            float4 yv;
            yv.x = fmaxf(b[0], 0.f); yv.y = fmaxf(b[1], 0.f);
            yv.z = fmaxf(b[2], 0.f); yv.w = fmaxf(b[3], 0.f);
            *(float4*)&Y2[(size_t)n * 64 + q2 * 4] = yv;
        }
    }
}

// ---------------------------------------------------------------------------
// k_mlp3: 64->64 (no relu), PURE GEMV (de-fused from head1: the fused
// version needed 184 VGPR -> 6.7% occupancy, 50 us; R11 showed capping
// spills. Split restores occupancy; head1 moves to k_head1p).
// ---------------------------------------------------------------------------
__global__ __launch_bounds__(256) void k_mlp3(
        const float* __restrict__ Y2, const float* __restrict__ W3,
        const float* __restrict__ b3, float* __restrict__ X3, int N) {
    __shared__ float w3[64 * 64];
    __shared__ float sb3[64];
    __shared__ float xs[32][68];
    int t = threadIdx.x;
    for (int i = t; i < 64 * 64; i += 256) w3[i] = W3[i];
    if (t < 64) sb3[t] = b3[t];
    int quad = t & 15, sub = t >> 4;
    int tiles = (N + 31) >> 5;
    for (int tile = blockIdx.x; tile < tiles; tile += gridDim.x) {
        int base = tile << 5;
        __syncthreads();
#pragma unroll
        for (int k = 0; k < 2; ++k) {
            int i = t + 256 * k;
            int nl = i >> 4, q = i & 15;
            int n = base + nl;
            float4 xv = make_float4(0.f, 0.f, 0.f, 0.f);
            if (n < N) xv = *(const float4*)&Y2[(size_t)n * 64 + q * 4];
            *(float4*)&xs[nl][q * 4] = xv;
        }
        __syncthreads();
        float a[2][4];
#pragma unroll
        for (int k = 0; k < 2; ++k)
#pragma unroll
            for (int c = 0; c < 4; ++c) a[k][c] = sb3[quad * 4 + c];
        for (int d = 0; d < 64; ++d) {
            float4 w4 = *(const float4*)&w3[d * 64 + quad * 4];
#pragma unroll
            for (int k = 0; k < 2; ++k) {
                float x = xs[sub * 2 + k][d];
                a[k][0] = fmaf(x, w4.x, a[k][0]);
                a[k][1] = fmaf(x, w4.y, a[k][1]);
                a[k][2] = fmaf(x, w4.z, a[k][2]);
                a[k][3] = fmaf(x, w4.w, a[k][3]);
            }
        }
#pragma unroll
        for (int k = 0; k < 2; ++k) {
            int n = base + sub * 2 + k;
            if (n < N)
                *(float4*)&X3[(size_t)n * 64 + quad * 4] = *(float4*)a[k];
        }
    }
}

// ---------------------------------------------------------------------------
// k_head1p: head1 on X3 (one node/thread), structured like k_head3p:
// logits1 + per-block lse partials + per-block gumbel argmax. X3 is
// L2/L3-warm from k_mlp3.
// ---------------------------------------------------------------------------
__global__ void k_head1p(const float* __restrict__ X3, const float* __restrict__ remW,
                         const float* __restrict__ remB, const int* __restrict__ active,
                         float* __restrict__ l1out, unsigned long long* __restrict__ slot1,
                         float2* __restrict__ part1, int N) {
    __shared__ float srw[64];
    __shared__ float redm[256], reds[256];
    __shared__ unsigned long long redb[256];
    int t = threadIdx.x;
    if (t < 64) srw[t] = remW[t];
    __syncthreads();
    int n = blockIdx.x * 256 + t;
    float lm = -INFINITY, ls = 0.f;
    unsigned long long best = 0ull;
    if (n < N) {
        const float* xr = X3 + (size_t)n * 64;
        float acc = remB[0];
        for (int d = 0; d < 64; d++) acc = fmaf(xr[d], srw[d], acc);
        float maskf = (active[n] == 1) ? 0.f : NEGF;
        float rm_ = (n < 15) ? ((maskf == 0.f) ? NEGF : 0.f) : maskf;
        float l1 = acc + rm_;
        l1out[n] = l1;
        lm = l1; ls = 1.f;
        float z = l1 + gumbel_at(n, 0, N);
        best = ((unsigned long long)fmono(z) << 32) |
               (unsigned long long)(0xFFFFFFFFu - (unsigned)n);
    }
    redm[t] = lm; reds[t] = ls; redb[t] = best;
    __syncthreads();
    for (int st = 128; st > 0; st >>= 1) {
        if (t < st) {
            float mm = redm[t], ss = reds[t];
            lse_merge(mm, ss, redm[t + st], reds[t + st]);
            redm[t] = mm; reds[t] = ss;
            if (redb[t + st] > redb[t]) redb[t] = redb[t + st];
        }
        __syncthreads();
    }
    if (t == 0) {
        part1[blockIdx.x] = make_float2(redm[0], reds[0]);
        if (redb[0]) atomicMax(slot1, redb[0]);
    }
}

// ---------------------------------------------------------------------------
// Head kernels
// ---------------------------------------------------------------------------
__global__ void k_head2(const float* __restrict__ X3, const float* __restrict__ addW,
                        const float* __restrict__ addB,
                        const unsigned long long* __restrict__ slot1,
                        float* __restrict__ tvec, int* __restrict__ a1buf) {
    int j = threadIdx.x;  // 64
    unsigned long long p = *slot1;
    int a1 = (int)(0xFFFFFFFFu - (unsigned)(p & 0xFFFFFFFFull));
    const float* xr = X3 + (size_t)a1 * 64;
    float acc = addB[j];
    for (int d = 0; d < 64; d++) acc = fmaf(xr[d], addW[d * 64 + j], acc);
    tvec[j] = tanhf(acc);
    if (j == 0) *a1buf = a1;
}

// head3 with per-block logsumexp partials + per-block argmax atomic.
__global__ void k_head3p(const float* __restrict__ X3, const float* __restrict__ tvec,
                         const int* __restrict__ active, const int* __restrict__ a1buf,
                         float* __restrict__ l2out, unsigned long long* __restrict__ slot2,
                         float2* __restrict__ part2, int N) {
    __shared__ float redm[256], reds[256];
    __shared__ unsigned long long redb[256];
    int t = threadIdx.x;
    int n = blockIdx.x * 256 + t;
    float lm = -INFINITY, ls = 0.f;
    unsigned long long best = 0ull;
    if (n < N) {
        const float* xr = X3 + (size_t)n * 64;
        float acc = 0.f;
        for (int d = 0; d < 64; d++) acc = fmaf(xr[d], tvec[d], acc);
        float maskf = (active[n] == 1) ? 0.f : NEGF;
        if (n == *a1buf) maskf = 0.f;
        float l2 = acc + maskf;
        l2out[n] = l2;
        lm = l2; ls = 1.f;
        float z = l2 + gumbel_at(n, 1, N);
        best = ((unsigned long long)fmono(z) << 32) |
               (unsigned long long)(0xFFFFFFFFu - (unsigned)n);
    }
    redm[t] = lm; reds[t] = ls; redb[t] = best;
    __syncthreads();
    for (int st = 128; st > 0; st >>= 1) {
        if (t < st) {
            float mm = redm[t], ss = reds[t];
            lse_merge(mm, ss, redm[t + st], reds[t + st]);
            redm[t] = mm; reds[t] = ss;
            if (redb[t + st] > redb[t]) redb[t] = redb[t + st];
        }
        __syncthreads();
    }
    if (t == 0) {
        part2[blockIdx.x] = make_float2(redm[0], reds[0]);
        if (redb[0]) atomicMax(slot2, redb[0]);
    }
}

__global__ void k_final2(const float* __restrict__ l1, const float* __restrict__ l2,
                         const unsigned long long* __restrict__ slot2,
                         const int* __restrict__ a1buf,
                         const float2* __restrict__ part1, int np1,
                         const float2* __restrict__ part2, int np2,
                         float* __restrict__ outTail) {
    __shared__ float rm[256], rs[256];
    int t = threadIdx.x;
    // reduce part1
    float m = -INFINITY, s = 0.f;
    for (int i = t; i < np1; i += 256) { float2 p = part1[i]; lse_merge(m, s, p.x, p.y); }
    rm[t] = m; rs[t] = s;
    __syncthreads();
    for (int st = 128; st > 0; st >>= 1) {
        if (t < st) { float mm = rm[t], ss = rs[t]; lse_merge(mm, ss, rm[t + st], rs[t + st]); rm[t] = mm; rs[t] = ss; }
        __syncthreads();
    }
    float M1 = rm[0], S1 = rs[0];
    __syncthreads();
    // reduce part2
    m = -INFINITY; s = 0.f;
    for (int i = t; i < np2; i += 256) { float2 p = part2[i]; lse_merge(m, s, p.x, p.y); }
    rm[t] = m; rs[t] = s;
    __syncthreads();
    for (int st = 128; st > 0; st >>= 1) {
        if (t < st) { float mm = rm[t], ss = rs[t]; lse_merge(mm, ss, rm[t + st], rs[t + st]); rm[t] = mm; rs[t] = ss; }
        __syncthreads();
    }
    float M2 = rm[0], S2 = rs[0];
    if (t == 0) {
        int a1 = *a1buf;
        int a2 = (int)(0xFFFFFFFFu - (unsigned)((*slot2) & 0xFFFFFFFFull));
        outTail[0] = (float)a1;
        outTail[1] = (float)a2;
        outTail[2] = l1[a1] - (M1 + logf(S1));
        outTail[3] = l2[a2] - (M2 + logf(S2));
    }
}

// ---------------------------------------------------------------------------
// Host launcher
// ---------------------------------------------------------------------------
extern "C" void kernel_launch(void* const* d_in, const int* in_sizes, int n_in,
                              void* d_out, int out_size, void* d_ws, size_t ws_size,
                              hipStream_t stream) {
    const float* node_type = (const float*)d_in[0];
    const float* requests  = (const float*)d_in[1];
    const float* latency   = (const float*)d_in[2];
    const int* edge_index  = (const int*)d_in[3];
    const int* active      = (const int*)d_in[4];
    int N = in_sizes[0];
    int E = in_sizes[2];
    const int* src = edge_index;
    const int* dst = edge_index + E;
    float* out = (float*)d_out;

    char* base = (char*)d_ws;
    size_t off = 0;
    auto alloc = [&](size_t bytes) -> char* {
        char* p = base + off;
        off += (bytes + 255) & ~(size_t)255;
        return p;
    };
    char* Abuf   = alloc((size_t)N * 128 * 4);  // fp16 A; later fp32 Y2
    char* Qbuf   = alloc((size_t)N * 128 * 4);  // fp16 Q
    __half* KV   = (__half*)alloc((size_t)N * 256 * 2); // interleaved K,V fp16
    char* Rbuf   = alloc((size_t)N * 128 * 4);  // fp16 R; later fp32 X3
    float* H32   = (float*)alloc((size_t)N * 32 * 4);
    int* deg     = (int*)alloc((size_t)N * 4);
    int* rowptr  = (int*)alloc((size_t)N * 4);
    int* cursor  = (int*)alloc((size_t)N * 4);
    int2* srclat = (int2*)alloc((size_t)E * 8);
    int* bsum    = (int*)alloc(1024 * 4);
    int lsTiles = (N + 63) / 64;
    double* partials = (double*)alloc((size_t)lsTiles * 64 * 8);
    double* SUM  = (double*)alloc(512);
    double* SUMSQ = SUM + 32;
    int ng = (N + 255) / 256;
    float2* part1 = (float2*)alloc((size_t)ng * 8);
    float2* part2 = (float2*)alloc((size_t)ng * 8);
    char* small  = alloc(1024);
    unsigned long long* slot1 = (unsigned long long*)small;
    unsigned long long* slot2 = slot1 + 1;
    int* a1buf = (int*)(small + 32);
    float* tvec = (float*)(small + 64);

    __half* Ah = (__half*)Abuf;   float* Y2f = (float*)Abuf;
    __half* Qh = (__half*)Qbuf;
    __half* Rh = (__half*)Rbuf;   float* X3f = (float*)Rbuf;

    int egE = (E + 255) / 256;
    int nb = ng;

    // ---- CSR build ----
    (void)hipMemsetAsync(deg, 0, (size_t)N * 4, stream);
    k_hist<<<egE, 256, 0, stream>>>(dst, deg, E);
    k_scan1<<<nb, 256, 0, stream>>>(deg, bsum, N);
    k_scan2<<<1, 256, 0, stream>>>(bsum, nb);
    k_scan3<<<nb, 256, 0, stream>>>(deg, bsum, rowptr, cursor, N);
    k_fill<<<egE, 256, 0, stream>>>(dst, src, latency, cursor, srclat, E);

    for (int L = 0; L < 5; ++L) {
        int din = L ? 32 : 2;
        const float* xin = L ? H32 : nullptr;
        const float* Wq = L ? (const float*)d_in[19] + (size_t)(L - 1) * 4096 : (const float*)d_in[5];
        const float* bq = L ? (const float*)d_in[20] + (size_t)(L - 1) * 128  : (const float*)d_in[6];
        const float* Wk = L ? (const float*)d_in[21] + (size_t)(L - 1) * 4096 : (const float*)d_in[7];
        const float* bk = L ? (const float*)d_in[22] + (size_t)(L - 1) * 128  : (const float*)d_in[8];
        const float* Wv = L ? (const float*)d_in[23] + (size_t)(L - 1) * 4096 : (const float*)d_in[9];
        const float* bv = L ? (const float*)d_in[24] + (size_t)(L - 1) * 128  : (const float*)d_in[10];
        const float* We = L ? (const float*)d_in[25] + (size_t)(L - 1) * 128  : (const float*)d_in[11];
        const float* Ws = L ? (const float*)d_in[26] + (size_t)(L - 1) * 4096 : (const float*)d_in[12];
        const float* bs = L ? (const float*)d_in[27] + (size_t)(L - 1) * 128  : (const float*)d_in[13];
        const float* Wb = L ? (const float*)d_in[28] + (size_t)(L - 1) * 384  : (const float*)d_in[14];
        const float* tW = L ? (const float*)d_in[29] + (size_t)(L - 1) * 4096 : (const float*)d_in[15];
        const float* tb = L ? (const float*)d_in[30] + (size_t)(L - 1) * 32   : (const float*)d_in[16];
        const float* bngP = (L == 1) ? (const float*)d_in[17]
                          : (L >= 2) ? (const float*)d_in[31] + (size_t)(L - 2) * 32 : nullptr;
        const float* bnbP = (L == 1) ? (const float*)d_in[18]
                          : (L >= 2) ? (const float*)d_in[32] + (size_t)(L - 2) * 32 : nullptr;

        k_qkvr<<<1024, 512, 0, stream>>>(xin, node_type, requests, din, N,
                                         Wq, bq, Wk, bk, Wv, bv, Ws, bs,
                                         SUM, SUMSQ, bngP, bnbP, (L > 0) ? 1 : 0,
                                         Qh, KV, Rh);
        k_attn<<<ATTNGRID, 256, 0, stream>>>(srclat, Qh, KV, We, Rh, Wb,
                                             rowptr, deg, Ah, N);
        k_linstats<<<lsTiles, 256, 0, stream>>>(Ah, tW, tb, H32, partials, N);
        k_statred<<<64, 256, 0, stream>>>(partials, SUM, SUMSQ, lsTiles);
    }

    // embedding MLP: H32 -> (Y1 in LDS) -> Y2(Abuf) -> X3(Rbuf); then heads
    k_mlp12<<<512, 256, 0, stream>>>(H32, SUM, SUMSQ,
                                     (const float*)d_in[31] + 3 * 32,
                                     (const float*)d_in[32] + 3 * 32,
                                     (const float*)d_in[33], (const float*)d_in[34],
                                     (const float*)d_in[35], (const float*)d_in[36],
                                     Y2f, (unsigned int*)small, N);
    k_mlp3<<<512, 256, 0, stream>>>(Y2f, (const float*)d_in[37], (const float*)d_in[38],
                                    X3f, N);
    k_head1p<<<ng, 256, 0, stream>>>(X3f, (const float*)d_in[39], (const float*)d_in[40],
                                     active, out, slot1, part1, N);
    k_head2<<<1, 64, 0, stream>>>(X3f, (const float*)d_in[41], (const float*)d_in[42],
                                  slot1, tvec, a1buf);
    k_head3p<<<ng, 256, 0, stream>>>(X3f, tvec, active, a1buf, out + N, slot2,
                                     part2, N);
    k_final2<<<1, 256, 0, stream>>>(out, out + N, slot2, a1buf,
                                    part1, ng, part2, ng, out + 2 * N);
}